// Round 2
// baseline (1121.704 us; speedup 1.0000x reference)
//
#include <hip/hip_runtime.h>
#include <math.h>

// ---------------------------------------------------------------------------
// GCN-VAE forward for MI355X — round 2.
// conv1 rewritten: embW1 = emb@W1 (128x256, 128KB, L2-resident), then
//   h1 = relu(agg over embW1[x[src]] + b1)  -- GEMM1 deleted.
// conv2 agg rewritten: feature-chunked (16 floats/chunk) so the gather slice
//   (3.2 MB) fits per-XCD L2; chunk = blockIdx.y (slowest) for residency.
// ---------------------------------------------------------------------------

__global__ __launch_bounds__(256) void k_init(int* __restrict__ degint,
                                              int* __restrict__ cursor, int N) {
    int i = blockIdx.x * 256 + threadIdx.x;
    if (i < N) { degint[i] = 1; cursor[i] = 0; }   // 1 = self-loop
}

__global__ __launch_bounds__(256) void k_deg_count(const int* __restrict__ dst,
                                                   int* __restrict__ degint, int E) {
    int e = blockIdx.x * 256 + threadIdx.x;
    if (e < E) atomicAdd(&degint[dst[e]], 1);
}

__global__ __launch_bounds__(256) void k_dinv(const int* __restrict__ degint,
                                              float* __restrict__ dinv, int N) {
    int i = blockIdx.x * 256 + threadIdx.x;
    if (i < N) dinv[i] = rsqrtf((float)degint[i]);
}

// ---- 3-kernel exclusive scan of (degint[i]-1) -> row_ptr -------------------
#define SCAN_BLOCK 1024
__global__ __launch_bounds__(SCAN_BLOCK) void k_scan_local(
        const int* __restrict__ degint, int* __restrict__ row_ptr,
        int* __restrict__ bsum, int N) {
    __shared__ int s[SCAN_BLOCK];
    int gid = blockIdx.x * SCAN_BLOCK + threadIdx.x;
    int v = (gid < N) ? (degint[gid] - 1) : 0;
    s[threadIdx.x] = v;
    __syncthreads();
    for (int off = 1; off < SCAN_BLOCK; off <<= 1) {
        int t = (threadIdx.x >= off) ? s[threadIdx.x - off] : 0;
        __syncthreads();
        s[threadIdx.x] += t;
        __syncthreads();
    }
    if (gid < N) row_ptr[gid] = s[threadIdx.x] - v;          // exclusive
    if (threadIdx.x == SCAN_BLOCK - 1) bsum[blockIdx.x] = s[SCAN_BLOCK - 1];
}

__global__ void k_scan_bsum(int* __restrict__ bsum, int nb) {
    if (blockIdx.x == 0 && threadIdx.x == 0) {
        int acc = 0;
        for (int i = 0; i < nb; ++i) { int v = bsum[i]; bsum[i] = acc; acc += v; }
    }
}

__global__ __launch_bounds__(256) void k_scan_add(int* __restrict__ row_ptr,
                                                  const int* __restrict__ bsum,
                                                  int N, int E) {
    int gid = blockIdx.x * 256 + threadIdx.x;
    if (gid < N) row_ptr[gid] += bsum[gid / SCAN_BLOCK];
    if (gid == 0) row_ptr[N] = E;
}

__global__ __launch_bounds__(256) void k_csr_fill(
        const int* __restrict__ src, const int* __restrict__ dst,
        const int* __restrict__ row_ptr, int* __restrict__ cursor,
        int* __restrict__ csr_src, int E) {
    int e = blockIdx.x * 256 + threadIdx.x;
    if (e < E) {
        int d = dst[e];
        int pos = atomicAdd(&cursor[d], 1);
        csr_src[row_ptr[d] + pos] = src[e];
    }
}

// ---- tiled fp32 GEMM: C[M,Ncol] = A[M,K] @ B[K,Ncol] (+bias)(relu) ---------
template<bool GATHER, bool RELU, bool BIAS>
__global__ __launch_bounds__(256) void k_gemm(
        const float* __restrict__ A, const int* __restrict__ idx,
        const float* __restrict__ B, const float* __restrict__ bias,
        float* __restrict__ C, int M, int K, int Ncol) {
    constexpr int BM = 64, BN = 64, BK = 16;
    __shared__ float As[BK][BM];   // transposed A tile
    __shared__ float Bs[BK][BN];
    const int tid = threadIdx.x;
    const int tx = tid & 15, ty = tid >> 4;
    const int rowBase = blockIdx.x * BM;
    const int colBase = blockIdx.y * BN;
    const int lr = tid >> 2, lc4 = tid & 3;   // A tile: 64 rows x 4 float4
    const int br = tid >> 4, bc4 = tid & 15;  // B tile: 16 rows x 16 float4
    const int arow = rowBase + lr;
    int asrc = arow;
    if (GATHER) asrc = (arow < M) ? idx[arow] : 0;
    const int K4 = K >> 2, N4 = Ncol >> 2;
    const float4* A4 = (const float4*)A;
    const float4* B4 = (const float4*)B;
    float acc[4][4] = {{0.f}};
    for (int k0 = 0; k0 < K; k0 += BK) {
        float4 av = make_float4(0.f, 0.f, 0.f, 0.f);
        if (arow < M) av = A4[(long)asrc * K4 + (k0 >> 2) + lc4];
        As[lc4 * 4 + 0][lr] = av.x;
        As[lc4 * 4 + 1][lr] = av.y;
        As[lc4 * 4 + 2][lr] = av.z;
        As[lc4 * 4 + 3][lr] = av.w;
        float4 bv = B4[(long)(k0 + br) * N4 + (colBase >> 2) + bc4];
        *(float4*)&Bs[br][bc4 * 4] = bv;
        __syncthreads();
#pragma unroll
        for (int k = 0; k < BK; ++k) {
            float4 a4v = *(const float4*)&As[k][ty * 4];
            float4 b4v = *(const float4*)&Bs[k][tx * 4];
            float aa[4] = {a4v.x, a4v.y, a4v.z, a4v.w};
            float bb[4] = {b4v.x, b4v.y, b4v.z, b4v.w};
#pragma unroll
            for (int i = 0; i < 4; ++i)
#pragma unroll
                for (int j = 0; j < 4; ++j)
                    acc[i][j] = fmaf(aa[i], bb[j], acc[i][j]);
        }
        __syncthreads();
    }
    float4 bb4 = make_float4(0.f, 0.f, 0.f, 0.f);
    if (BIAS) bb4 = ((const float4*)bias)[(colBase >> 2) + tx];
#pragma unroll
    for (int i = 0; i < 4; ++i) {
        int row = rowBase + ty * 4 + i;
        if (row < M) {
            float4 o;
            o.x = acc[i][0] + bb4.x; o.y = acc[i][1] + bb4.y;
            o.z = acc[i][2] + bb4.z; o.w = acc[i][3] + bb4.w;
            if (RELU) {
                o.x = fmaxf(o.x, 0.f); o.y = fmaxf(o.y, 0.f);
                o.z = fmaxf(o.z, 0.f); o.w = fmaxf(o.w, 0.f);
            }
            ((float4*)C)[(long)row * N4 + (colBase >> 2) + tx] = o;
        }
    }
}

// ---- conv1 aggregation via 128-row L2-resident table -----------------------
// out[i] = relu(b1 + di*sum_s dinv[s]*T[x[s]] + di^2*T[x[i]]), T=embW1 [V,256]
// One wave per node, lane = float4 feature slot (64*16B = 1KB row).
__global__ __launch_bounds__(256) void k_agg_idx(
        const float* __restrict__ table, const int* __restrict__ x,
        const int* __restrict__ row_ptr, const int* __restrict__ csr_src,
        const float* __restrict__ dinv, const float* __restrict__ bias,
        float* __restrict__ out, int N) {
    const int wave = threadIdx.x >> 6;
    const int lane = threadIdx.x & 63;
    const int node = blockIdx.x * 4 + wave;
    if (node >= N) return;
    const float4* t4 = (const float4*)table;
    const float di = dinv[node];
    const float selfw = di * di;
    float4 a = t4[(long)x[node] * 64 + lane];
    float4 acc;
    acc.x = a.x * selfw; acc.y = a.y * selfw;
    acc.z = a.z * selfw; acc.w = a.w * selfw;
    const int beg = row_ptr[node], end = row_ptr[node + 1];
    for (int e = beg; e < end; ++e) {
        int s = csr_src[e];
        float w = dinv[s] * di;
        float4 v = t4[(long)x[s] * 64 + lane];
        acc.x = fmaf(v.x, w, acc.x); acc.y = fmaf(v.y, w, acc.y);
        acc.z = fmaf(v.z, w, acc.z); acc.w = fmaf(v.w, w, acc.w);
    }
    float4 b = ((const float4*)bias)[lane];
    acc.x = fmaxf(acc.x + b.x, 0.f); acc.y = fmaxf(acc.y + b.y, 0.f);
    acc.z = fmaxf(acc.z + b.z, 0.f); acc.w = fmaxf(acc.w + b.w, 0.f);
    ((float4*)out)[(long)node * 64 + lane] = acc;
}

// ---- conv2 aggregation, feature-chunked for L2 residency -------------------
// Chunk = 16 floats; table slice = N*64B = 3.2MB < 4MB L2/XCD.
// Wave per node; lane = (esub<<4)|feat: 4 edges x 16 feats in parallel.
// grid = (ceil(N/4), 16); blockIdx.y (chunk) is slowest-varying.
__global__ __launch_bounds__(256) void k_agg_chunk(
        const float* __restrict__ hW, const int* __restrict__ row_ptr,
        const int* __restrict__ csr_src, const float* __restrict__ dinv,
        const float* __restrict__ bias, float* __restrict__ out, int N) {
    const int wave = threadIdx.x >> 6;
    const int lane = threadIdx.x & 63;
    const int node = blockIdx.x * 4 + wave;
    if (node >= N) return;
    const int feat = (blockIdx.y << 4) | (lane & 15);
    const int esub = lane >> 4;                  // 0..3
    const float di = dinv[node];
    float acc = (esub == 0) ? hW[(long)node * 256 + feat] * di * di : 0.f;
    const int beg = row_ptr[node], end = row_ptr[node + 1];
    for (int e0 = beg; e0 < end; e0 += 4) {
        int e = e0 + esub;
        bool ok = (e < end);
        int s = csr_src[ok ? e : beg];
        float w = ok ? dinv[s] * di : 0.f;
        acc = fmaf(hW[(long)s * 256 + feat], w, acc);
    }
    acc += __shfl_xor(acc, 16, 64);
    acc += __shfl_xor(acc, 32, 64);
    if (esub == 0) {
        acc += bias[feat];
        out[(long)node * 256 + feat] = fmaxf(acc, 0.f);
    }
}

// ---- z = mu + eps * exp(0.5*logvar) ---------------------------------------
__global__ __launch_bounds__(256) void k_z(
        const float* __restrict__ mu, const float* __restrict__ lv,
        const float* __restrict__ eps, float* __restrict__ z, int n) {
    int i = blockIdx.x * 256 + threadIdx.x;
    if (i < n) z[i] = fmaf(eps[i], expf(0.5f * lv[i]), mu[i]);
}

// ---- capitalize = sigmoid(z @ Wcap + bcap) --------------------------------
__global__ __launch_bounds__(256) void k_cap(
        const float* __restrict__ z, const float* __restrict__ Wcap,
        const float* __restrict__ bcap, float* __restrict__ out, int N) {
    const int wave = threadIdx.x >> 6;
    const int lane = threadIdx.x & 63;
    const int node = blockIdx.x * 4 + wave;
    if (node >= N) return;
    float v = z[(long)node * 64 + lane] * Wcap[lane];
    for (int off = 32; off; off >>= 1) v += __shfl_down(v, off, 64);
    if (lane == 0) out[node] = 1.f / (1.f + expf(-(v + bcap[0])));
}

extern "C" void kernel_launch(void* const* d_in, const int* in_sizes, int n_in,
                              void* d_out, int out_size, void* d_ws, size_t ws_size,
                              hipStream_t stream) {
    const int*   x    = (const int*)d_in[0];
    const int*   ei   = (const int*)d_in[1];
    const float* eps  = (const float*)d_in[2];
    const float* emb  = (const float*)d_in[3];
    const float* W1   = (const float*)d_in[4];
    const float* b1   = (const float*)d_in[5];
    const float* W2   = (const float*)d_in[6];
    const float* b2   = (const float*)d_in[7];
    const float* Wmu  = (const float*)d_in[8];
    const float* bmu  = (const float*)d_in[9];
    const float* Wlv  = (const float*)d_in[10];
    const float* blv  = (const float*)d_in[11];
    const float* W3   = (const float*)d_in[12];
    const float* b3   = (const float*)d_in[13];
    const float* W4   = (const float*)d_in[14];
    const float* b4   = (const float*)d_in[15];
    const float* Wcap = (const float*)d_in[16];
    const float* bcap = (const float*)d_in[17];

    const int N = in_sizes[0];
    const int E = in_sizes[1] / 2;
    const int H = in_sizes[5];            // 256
    const int L = in_sizes[9];            // 64
    const int V = in_sizes[15];           // 128
    const int F = in_sizes[4] / H;        // 128

    const int* src = ei;
    const int* dst = ei + E;

    // ---- workspace carve-up ----
    char* w = (char*)d_ws;
    float* bufA   = (float*)w; w += (size_t)N * H * 4;       // hW2 / z
    float* bufB   = (float*)w; w += (size_t)N * H * 4;       // h1 / h2 / t
    int*   degint = (int*)w;   w += (size_t)N * 4;
    int*   rowp   = (int*)w;   w += (size_t)(N + 1) * 4;
    int*   cursor = (int*)w;   w += (size_t)N * 4;
    float* dinv   = (float*)w; w += (size_t)N * 4;
    int*   bsum   = (int*)w;   w += 256 * 4;
    int*   csrsrc = (int*)w;   w += (size_t)E * 4;
    float* embW1  = (float*)w; w += (size_t)V * H * 4;       // 128x256 table

    float* outp    = (float*)d_out;
    float* recon   = outp;                               // [N, V]
    float* cap     = outp + (size_t)N * V;               // [N, 1]
    float* mu      = outp + (size_t)N * V + N;           // [N, L]
    float* logvar  = mu + (size_t)N * L;                 // [N, L]
    float* z       = bufA;                               // [N, L]

    const int nN  = (N + 255) / 256;
    const int nE  = (E + 255) / 256;
    const int nSc = (N + SCAN_BLOCK - 1) / SCAN_BLOCK;
    const int gM  = (N + 63) / 64;

    // ---- degree / dinv / CSR ----
    k_init<<<nN, 256, 0, stream>>>(degint, cursor, N);
    k_deg_count<<<nE, 256, 0, stream>>>(dst, degint, E);
    k_dinv<<<nN, 256, 0, stream>>>(degint, dinv, N);
    k_scan_local<<<nSc, SCAN_BLOCK, 0, stream>>>(degint, rowp, bsum, N);
    k_scan_bsum<<<1, 64, 0, stream>>>(bsum, nSc);
    k_scan_add<<<nN, 256, 0, stream>>>(rowp, bsum, N, E);
    k_csr_fill<<<nE, 256, 0, stream>>>(src, dst, rowp, cursor, csrsrc, E);

    // ---- conv1: embW1 = emb @ W1 (tiny), then table-gather aggregation ----
    k_gemm<false, false, false><<<dim3(V / 64, H / 64), 256, 0, stream>>>(
        emb, nullptr, W1, nullptr, embW1, V, F, H);
    k_agg_idx<<<(N + 3) / 4, 256, 0, stream>>>(
        embW1, x, rowp, csrsrc, dinv, b1, bufB, N);

    // ---- conv2: hW2 = h1 @ W2 ; h2 = relu(chunked agg + b2) ----
    k_gemm<false, false, false><<<dim3(gM, H / 64), 256, 0, stream>>>(
        bufB, nullptr, W2, nullptr, bufA, N, H, H);
    k_agg_chunk<<<dim3((N + 3) / 4, H / 16), 256, 0, stream>>>(
        bufA, rowp, csrsrc, dinv, b2, bufB, N);

    // ---- heads: mu, logvar ----
    k_gemm<false, false, true><<<dim3(gM, L / 64), 256, 0, stream>>>(
        bufB, nullptr, Wmu, bmu, mu, N, H, L);
    k_gemm<false, false, true><<<dim3(gM, L / 64), 256, 0, stream>>>(
        bufB, nullptr, Wlv, blv, logvar, N, H, L);

    // ---- reparameterize ----
    k_z<<<(N * L + 255) / 256, 256, 0, stream>>>(mu, logvar, eps, z, N * L);

    // ---- decode: t = relu(z@W3+b3); recon = t@W4+b4 ----
    k_gemm<false, true,  true><<<dim3(gM, H / 64), 256, 0, stream>>>(
        z, nullptr, W3, b3, bufB, N, L, H);
    k_gemm<false, false, true><<<dim3(gM, V / 64), 256, 0, stream>>>(
        bufB, nullptr, W4, b4, recon, N, H, V);

    // ---- capitalize head ----
    k_cap<<<(N + 3) / 4, 256, 0, stream>>>(z, Wcap, bcap, cap, N);
}

// Round 4
// 582.927 us; speedup vs baseline: 1.9243x; 1.9243x over previous
//
#include <hip/hip_runtime.h>
#include <math.h>

// ---------------------------------------------------------------------------
// GCN-VAE forward, round 4 = round 3 + staging-width fix.
// R3 bug: LDS tile staging wrote 8 shorts per thread at short-offsets {0,16},
// leaving cols 8-15/24-31 of every 32-wide K-slice unwritten (garbage ->
// NaN chain). Now each thread stages 16 consecutive shorts (two bf16x8).
// ---------------------------------------------------------------------------

typedef __attribute__((ext_vector_type(8))) short bf16x8;
typedef __attribute__((ext_vector_type(4))) float f32x4;

__device__ inline unsigned short f2bf(float x) {
    unsigned u = __float_as_uint(x);
    return (unsigned short)((u + 0x7FFFu + ((u >> 16) & 1u)) >> 16);
}
__device__ inline float bf2f(unsigned short h) {
    return __uint_as_float(((unsigned)h) << 16);
}

// ============================ CSR build ====================================
__global__ __launch_bounds__(256) void k_init(int* __restrict__ degint,
                                              int* __restrict__ cursor, int N) {
    int i = blockIdx.x * 256 + threadIdx.x;
    if (i < N) { degint[i] = 1; cursor[i] = 0; }   // 1 = self-loop
}

__global__ __launch_bounds__(256) void k_deg_count(const int* __restrict__ dst,
                                                   int* __restrict__ degint, int E) {
    int e = blockIdx.x * 256 + threadIdx.x;
    if (e < E) atomicAdd(&degint[dst[e]], 1);
}

__global__ __launch_bounds__(256) void k_dinv(const int* __restrict__ degint,
                                              float* __restrict__ dinv, int N) {
    int i = blockIdx.x * 256 + threadIdx.x;
    if (i < N) dinv[i] = rsqrtf((float)degint[i]);
}

#define SCAN_BLOCK 1024
__global__ __launch_bounds__(SCAN_BLOCK) void k_scan_local(
        const int* __restrict__ degint, int* __restrict__ row_ptr,
        int* __restrict__ bsum, int N) {
    __shared__ int s[SCAN_BLOCK];
    int gid = blockIdx.x * SCAN_BLOCK + threadIdx.x;
    int v = (gid < N) ? (degint[gid] - 1) : 0;
    s[threadIdx.x] = v;
    __syncthreads();
    for (int off = 1; off < SCAN_BLOCK; off <<= 1) {
        int t = (threadIdx.x >= off) ? s[threadIdx.x - off] : 0;
        __syncthreads();
        s[threadIdx.x] += t;
        __syncthreads();
    }
    if (gid < N) row_ptr[gid] = s[threadIdx.x] - v;          // exclusive
    if (threadIdx.x == SCAN_BLOCK - 1) bsum[blockIdx.x] = s[SCAN_BLOCK - 1];
}

__global__ void k_scan_bsum(int* __restrict__ bsum, int nb) {
    if (blockIdx.x == 0 && threadIdx.x == 0) {
        int acc = 0;
        for (int i = 0; i < nb; ++i) { int v = bsum[i]; bsum[i] = acc; acc += v; }
    }
}

__global__ __launch_bounds__(256) void k_scan_add(int* __restrict__ row_ptr,
                                                  const int* __restrict__ bsum,
                                                  int N, int E) {
    int gid = blockIdx.x * 256 + threadIdx.x;
    if (gid < N) row_ptr[gid] += bsum[gid / SCAN_BLOCK];
    if (gid == 0) row_ptr[N] = E;
}

__global__ __launch_bounds__(256) void k_csr_fill(
        const int* __restrict__ src, const int* __restrict__ dst,
        const int* __restrict__ row_ptr, int* __restrict__ cursor,
        int* __restrict__ csr_src, int E) {
    int e = blockIdx.x * 256 + threadIdx.x;
    if (e < E) {
        int d = dst[e];
        int pos = atomicAdd(&cursor[d], 1);
        csr_src[row_ptr[d] + pos] = src[e];
    }
}

// ============ weight transpose + hi/lo split: B[K,N] -> Bt{h,l}[N,K] =======
__global__ __launch_bounds__(256) void k_cvtB(
        const float* __restrict__ B, unsigned short* __restrict__ Bth,
        unsigned short* __restrict__ Btl, int K, int Ncol) {
    int i = blockIdx.x * 256 + threadIdx.x;
    if (i >= K * Ncol) return;
    int k = i / Ncol, n = i - k * Ncol;
    float v = B[i];
    unsigned short h = f2bf(v);
    Bth[(long)n * K + k] = h;
    Btl[(long)n * K + k] = f2bf(v - bf2f(h));
}

// ================= small fp32 GEMM (embW1 = emb @ W1 only) =================
__global__ __launch_bounds__(256) void k_gemm_f32(
        const float* __restrict__ A, const float* __restrict__ B,
        float* __restrict__ C, int M, int K, int Ncol) {
    constexpr int BM = 64, BN = 64, BK = 16;
    __shared__ float As[BK][BM];
    __shared__ float Bs[BK][BN];
    const int tid = threadIdx.x;
    const int tx = tid & 15, ty = tid >> 4;
    const int rowBase = blockIdx.x * BM;
    const int colBase = blockIdx.y * BN;
    const int lr = tid >> 2, lc4 = tid & 3;
    const int br = tid >> 4, bc4 = tid & 15;
    const int arow = rowBase + lr;
    const int K4 = K >> 2, N4 = Ncol >> 2;
    const float4* A4 = (const float4*)A;
    const float4* B4 = (const float4*)B;
    float acc[4][4] = {{0.f}};
    for (int k0 = 0; k0 < K; k0 += BK) {
        float4 av = make_float4(0.f, 0.f, 0.f, 0.f);
        if (arow < M) av = A4[(long)arow * K4 + (k0 >> 2) + lc4];
        As[lc4 * 4 + 0][lr] = av.x;
        As[lc4 * 4 + 1][lr] = av.y;
        As[lc4 * 4 + 2][lr] = av.z;
        As[lc4 * 4 + 3][lr] = av.w;
        float4 bv = B4[(long)(k0 + br) * N4 + (colBase >> 2) + bc4];
        *(float4*)&Bs[br][bc4 * 4] = bv;
        __syncthreads();
#pragma unroll
        for (int k = 0; k < BK; ++k) {
            float4 a4v = *(const float4*)&As[k][ty * 4];
            float4 b4v = *(const float4*)&Bs[k][tx * 4];
            float aa[4] = {a4v.x, a4v.y, a4v.z, a4v.w};
            float bb[4] = {b4v.x, b4v.y, b4v.z, b4v.w};
#pragma unroll
            for (int i = 0; i < 4; ++i)
#pragma unroll
                for (int j = 0; j < 4; ++j)
                    acc[i][j] = fmaf(aa[i], bb[j], acc[i][j]);
        }
        __syncthreads();
    }
#pragma unroll
    for (int i = 0; i < 4; ++i) {
        int row = rowBase + ty * 4 + i;
        if (row < M) {
            float4 o = make_float4(acc[i][0], acc[i][1], acc[i][2], acc[i][3]);
            ((float4*)C)[(long)row * N4 + (colBase >> 2) + tx] = o;
        }
    }
}

// ================= MFMA GEMM with bf16 hi/lo split =========================
// C[M,Ncol] = A[M,K] @ B[K,Ncol]; A given as (Ah,Al) bf16 [M,K] row-major;
// B given as (Bth,Btl) bf16 [Ncol,K] (transposed). BM=128 BN=64 BK=32,
// 256 threads = 4 waves; wave w owns rows [w*32, w*32+32) x all 64 cols.
template<bool RELU, bool BIAS, bool OUTPAIR>
__global__ __launch_bounds__(256) void k_gemm_mfma(
        const unsigned short* __restrict__ Ah, const unsigned short* __restrict__ Al,
        const unsigned short* __restrict__ Bth, const unsigned short* __restrict__ Btl,
        const float* __restrict__ bias, float* __restrict__ Cf,
        unsigned short* __restrict__ Ch, unsigned short* __restrict__ Cl,
        int M, int K, int Ncol) {
    __shared__ unsigned short Ash[128][40];   // row stride 80B: b128 2-way (free)
    __shared__ unsigned short Asl[128][40];
    __shared__ unsigned short Bsh[64][40];
    __shared__ unsigned short Bsl[64][40];
    const int tid = threadIdx.x;
    const int lane = tid & 63, w = tid >> 6;
    const int fr = lane & 15, quad = lane >> 4;
    const int wm0 = w * 32;
    const int rowBase = blockIdx.x * 128;
    const int colBase = blockIdx.y * 64;

    // staging maps: each thread covers 16 consecutive k (32 B = 2x bf16x8)
    const int arow = tid >> 1;                 // 0..127
    const int ahalf = (tid & 1) << 4;          // 0 | 16 (shorts)
    int agrow = rowBase + arow; if (agrow >= M) agrow = M - 1;
    const long abase = (long)agrow * K + ahalf;
    const int bt = tid & 127;
    const int brow = bt >> 1;                  // 0..63
    const int bhalf = (bt & 1) << 4;
    const long bbase = (long)(colBase + brow) * K + bhalf;
    const unsigned short* Bsrc = (tid < 128) ? Bth : Btl;
    unsigned short* Bdst = (tid < 128) ? &Bsh[brow][bhalf] : &Bsl[brow][bhalf];

    f32x4 acc[2][4];
#pragma unroll
    for (int i = 0; i < 2; ++i)
#pragma unroll
        for (int j = 0; j < 4; ++j) acc[i][j] = (f32x4){0.f, 0.f, 0.f, 0.f};

    for (int k0 = 0; k0 < K; k0 += 32) {
        *(bf16x8*)&Ash[arow][ahalf]     = *(const bf16x8*)&Ah[abase + k0];
        *(bf16x8*)&Ash[arow][ahalf + 8] = *(const bf16x8*)&Ah[abase + k0 + 8];
        *(bf16x8*)&Asl[arow][ahalf]     = *(const bf16x8*)&Al[abase + k0];
        *(bf16x8*)&Asl[arow][ahalf + 8] = *(const bf16x8*)&Al[abase + k0 + 8];
        *(bf16x8*)Bdst       = *(const bf16x8*)&Bsrc[bbase + k0];
        *(bf16x8*)(Bdst + 8) = *(const bf16x8*)&Bsrc[bbase + k0 + 8];
        __syncthreads();
        bf16x8 ahf[2], alf[2], bhf[4], blf[4];
#pragma unroll
        for (int i = 0; i < 2; ++i) {
            ahf[i] = *(const bf16x8*)&Ash[wm0 + i * 16 + fr][quad * 8];
            alf[i] = *(const bf16x8*)&Asl[wm0 + i * 16 + fr][quad * 8];
        }
#pragma unroll
        for (int j = 0; j < 4; ++j) {
            bhf[j] = *(const bf16x8*)&Bsh[j * 16 + fr][quad * 8];
            blf[j] = *(const bf16x8*)&Bsl[j * 16 + fr][quad * 8];
        }
#pragma unroll
        for (int i = 0; i < 2; ++i)
#pragma unroll
            for (int j = 0; j < 4; ++j) {
                acc[i][j] = __builtin_amdgcn_mfma_f32_16x16x32_bf16(
                    ahf[i], bhf[j], acc[i][j], 0, 0, 0);
                acc[i][j] = __builtin_amdgcn_mfma_f32_16x16x32_bf16(
                    ahf[i], blf[j], acc[i][j], 0, 0, 0);
                acc[i][j] = __builtin_amdgcn_mfma_f32_16x16x32_bf16(
                    alf[i], bhf[j], acc[i][j], 0, 0, 0);
            }
        __syncthreads();
    }

    // epilogue: C layout col=lane&15, row=quad*4+reg
#pragma unroll
    for (int i = 0; i < 2; ++i) {
        const int rowb = rowBase + wm0 + i * 16 + quad * 4;
#pragma unroll
        for (int j = 0; j < 4; ++j) {
            const int col = colBase + j * 16 + fr;
            const float bv = BIAS ? bias[col] : 0.f;
#pragma unroll
            for (int r = 0; r < 4; ++r) {
                const int row = rowb + r;
                if (row < M) {
                    float v = acc[i][j][r] + bv;
                    if (RELU) v = fmaxf(v, 0.f);
                    const long o = (long)row * Ncol + col;
                    if (OUTPAIR) {
                        unsigned short h = f2bf(v);
                        Ch[o] = h;
                        Cl[o] = f2bf(v - bf2f(h));
                    } else {
                        Cf[o] = v;
                    }
                }
            }
        }
    }
}

// ========= conv1 aggregation from 128-row table, pair output ===============
__global__ __launch_bounds__(256) void k_agg_idx_pair(
        const float* __restrict__ table, const int* __restrict__ x,
        const int* __restrict__ row_ptr, const int* __restrict__ csr_src,
        const float* __restrict__ dinv, const float* __restrict__ bias,
        unsigned short* __restrict__ Oh, unsigned short* __restrict__ Ol, int N) {
    const int wave = threadIdx.x >> 6;
    const int lane = threadIdx.x & 63;
    const int node = blockIdx.x * 4 + wave;
    if (node >= N) return;
    const float4* t4 = (const float4*)table;
    const float di = dinv[node];
    const float selfw = di * di;
    float4 a = t4[(long)x[node] * 64 + lane];
    float4 acc;
    acc.x = a.x * selfw; acc.y = a.y * selfw;
    acc.z = a.z * selfw; acc.w = a.w * selfw;
    const int beg = row_ptr[node], end = row_ptr[node + 1];
    for (int e = beg; e < end; ++e) {
        int s = csr_src[e];
        float wgt = dinv[s] * di;
        float4 v = t4[(long)x[s] * 64 + lane];
        acc.x = fmaf(v.x, wgt, acc.x); acc.y = fmaf(v.y, wgt, acc.y);
        acc.z = fmaf(v.z, wgt, acc.z); acc.w = fmaf(v.w, wgt, acc.w);
    }
    float4 b = ((const float4*)bias)[lane];
    acc.x = fmaxf(acc.x + b.x, 0.f); acc.y = fmaxf(acc.y + b.y, 0.f);
    acc.z = fmaxf(acc.z + b.z, 0.f); acc.w = fmaxf(acc.w + b.w, 0.f);
    const long base = (long)node * 256 + lane * 4;
    ushort4 hh, ll;
    hh.x = f2bf(acc.x); ll.x = f2bf(acc.x - bf2f(hh.x));
    hh.y = f2bf(acc.y); ll.y = f2bf(acc.y - bf2f(hh.y));
    hh.z = f2bf(acc.z); ll.z = f2bf(acc.z - bf2f(hh.z));
    hh.w = f2bf(acc.w); ll.w = f2bf(acc.w - bf2f(hh.w));
    *(ushort4*)&Oh[base] = hh;
    *(ushort4*)&Ol[base] = ll;
}

// ========= conv2 aggregation (R1 structure), pair output ===================
__global__ __launch_bounds__(256) void k_agg_pair(
        const float* __restrict__ hW, const int* __restrict__ row_ptr,
        const int* __restrict__ csr_src, const float* __restrict__ dinv,
        const float* __restrict__ bias,
        unsigned short* __restrict__ Oh, unsigned short* __restrict__ Ol, int N) {
    const int wave = threadIdx.x >> 6;
    const int lane = threadIdx.x & 63;
    const int node = blockIdx.x * 4 + wave;
    if (node >= N) return;
    const float4* hw4 = (const float4*)hW;
    const float di = dinv[node];
    const float selfw = di * di;
    float4 a = hw4[(long)node * 64 + lane];
    float4 acc;
    acc.x = a.x * selfw; acc.y = a.y * selfw;
    acc.z = a.z * selfw; acc.w = a.w * selfw;
    const int beg = row_ptr[node], end = row_ptr[node + 1];
    for (int e = beg; e < end; ++e) {
        int s = csr_src[e];
        float wgt = dinv[s] * di;
        float4 v = hw4[(long)s * 64 + lane];
        acc.x = fmaf(v.x, wgt, acc.x); acc.y = fmaf(v.y, wgt, acc.y);
        acc.z = fmaf(v.z, wgt, acc.z); acc.w = fmaf(v.w, wgt, acc.w);
    }
    float4 b = ((const float4*)bias)[lane];
    acc.x = fmaxf(acc.x + b.x, 0.f); acc.y = fmaxf(acc.y + b.y, 0.f);
    acc.z = fmaxf(acc.z + b.z, 0.f); acc.w = fmaxf(acc.w + b.w, 0.f);
    const long base = (long)node * 256 + lane * 4;
    ushort4 hh, ll;
    hh.x = f2bf(acc.x); ll.x = f2bf(acc.x - bf2f(hh.x));
    hh.y = f2bf(acc.y); ll.y = f2bf(acc.y - bf2f(hh.y));
    hh.z = f2bf(acc.z); ll.z = f2bf(acc.z - bf2f(hh.z));
    hh.w = f2bf(acc.w); ll.w = f2bf(acc.w - bf2f(hh.w));
    *(ushort4*)&Oh[base] = hh;
    *(ushort4*)&Ol[base] = ll;
}

// ---- z = mu + eps * exp(0.5*logvar), pair output --------------------------
__global__ __launch_bounds__(256) void k_z(
        const float* __restrict__ mu, const float* __restrict__ lv,
        const float* __restrict__ eps, unsigned short* __restrict__ Zh,
        unsigned short* __restrict__ Zl, int n) {
    int i = blockIdx.x * 256 + threadIdx.x;
    if (i < n) {
        float zz = fmaf(eps[i], expf(0.5f * lv[i]), mu[i]);
        unsigned short h = f2bf(zz);
        Zh[i] = h;
        Zl[i] = f2bf(zz - bf2f(h));
    }
}

// ---- capitalize = sigmoid(z @ Wcap + bcap) --------------------------------
__global__ __launch_bounds__(256) void k_cap(
        const unsigned short* __restrict__ Zh, const unsigned short* __restrict__ Zl,
        const float* __restrict__ Wcap, const float* __restrict__ bcap,
        float* __restrict__ out, int N) {
    const int wave = threadIdx.x >> 6;
    const int lane = threadIdx.x & 63;
    const int node = blockIdx.x * 4 + wave;
    if (node >= N) return;
    long idx = (long)node * 64 + lane;
    float v = (bf2f(Zh[idx]) + bf2f(Zl[idx])) * Wcap[lane];
    for (int off = 32; off; off >>= 1) v += __shfl_down(v, off, 64);
    if (lane == 0) out[node] = 1.f / (1.f + expf(-(v + bcap[0])));
}

extern "C" void kernel_launch(void* const* d_in, const int* in_sizes, int n_in,
                              void* d_out, int out_size, void* d_ws, size_t ws_size,
                              hipStream_t stream) {
    const int*   x    = (const int*)d_in[0];
    const int*   ei   = (const int*)d_in[1];
    const float* eps  = (const float*)d_in[2];
    const float* emb  = (const float*)d_in[3];
    const float* W1   = (const float*)d_in[4];
    const float* b1   = (const float*)d_in[5];
    const float* W2   = (const float*)d_in[6];
    const float* b2   = (const float*)d_in[7];
    const float* Wmu  = (const float*)d_in[8];
    const float* bmu  = (const float*)d_in[9];
    const float* Wlv  = (const float*)d_in[10];
    const float* blv  = (const float*)d_in[11];
    const float* W3   = (const float*)d_in[12];
    const float* b3   = (const float*)d_in[13];
    const float* W4   = (const float*)d_in[14];
    const float* b4   = (const float*)d_in[15];
    const float* Wcap = (const float*)d_in[16];
    const float* bcap = (const float*)d_in[17];

    const int N = in_sizes[0];
    const int E = in_sizes[1] / 2;
    const int H = in_sizes[5];            // 256
    const int L = in_sizes[9];            // 64
    const int V = in_sizes[15];           // 128
    const int F = in_sizes[4] / H;        // 128

    const int* src = ei;
    const int* dst = ei + E;

    // ---- workspace carve-up (large blocks first) ----
    char* w = (char*)d_ws;
    float* bufA = (float*)w;          w += (size_t)N * H * 4;   // hW2 fp32; later t-pair
    unsigned short* pairH = (unsigned short*)w; w += (size_t)N * H * 2; // h1h / h2h
    unsigned short* pairL = (unsigned short*)w; w += (size_t)N * H * 2; // h1l / h2l
    unsigned short* zh   = (unsigned short*)w; w += (size_t)N * L * 2;
    unsigned short* zl   = (unsigned short*)w; w += (size_t)N * L * 2;
    int*   degint = (int*)w;   w += (size_t)N * 4;
    int*   rowp   = (int*)w;   w += (size_t)(N + 1) * 4;
    int*   cursor = (int*)w;   w += (size_t)N * 4;
    float* dinv   = (float*)w; w += (size_t)N * 4;
    int*   bsum   = (int*)w;   w += 256 * 4;
    int*   csrsrc = (int*)w;   w += (size_t)E * 4;
    float* embW1  = (float*)w; w += (size_t)V * H * 4;
    unsigned short* W2th  = (unsigned short*)w; w += (size_t)H * H * 2;
    unsigned short* W2tl  = (unsigned short*)w; w += (size_t)H * H * 2;
    unsigned short* Wmuth = (unsigned short*)w; w += (size_t)H * L * 2;
    unsigned short* Wmutl = (unsigned short*)w; w += (size_t)H * L * 2;
    unsigned short* Wlvth = (unsigned short*)w; w += (size_t)H * L * 2;
    unsigned short* Wlvtl = (unsigned short*)w; w += (size_t)H * L * 2;
    unsigned short* W3th  = (unsigned short*)w; w += (size_t)L * H * 2;
    unsigned short* W3tl  = (unsigned short*)w; w += (size_t)L * H * 2;
    unsigned short* W4th  = (unsigned short*)w; w += (size_t)H * V * 2;
    unsigned short* W4tl  = (unsigned short*)w; w += (size_t)H * V * 2;

    // t-pair reuses bufA (hW2 dead after agg2)
    unsigned short* tH = (unsigned short*)bufA;
    unsigned short* tL = (unsigned short*)bufA + (size_t)N * H;

    float* outp    = (float*)d_out;
    float* recon   = outp;                               // [N, V]
    float* cap     = outp + (size_t)N * V;               // [N, 1]
    float* mu      = outp + (size_t)N * V + N;           // [N, L]
    float* logvar  = mu + (size_t)N * L;                 // [N, L]

    const int nN  = (N + 255) / 256;
    const int nE  = (E + 255) / 256;
    const int nSc = (N + SCAN_BLOCK - 1) / SCAN_BLOCK;
    const int gM  = (N + 127) / 128;

    // ---- degree / dinv / CSR ----
    k_init<<<nN, 256, 0, stream>>>(degint, cursor, N);
    k_deg_count<<<nE, 256, 0, stream>>>(dst, degint, E);
    k_dinv<<<nN, 256, 0, stream>>>(degint, dinv, N);
    k_scan_local<<<nSc, SCAN_BLOCK, 0, stream>>>(degint, rowp, bsum, N);
    k_scan_bsum<<<1, 64, 0, stream>>>(bsum, nSc);
    k_scan_add<<<nN, 256, 0, stream>>>(rowp, bsum, N, E);
    k_csr_fill<<<nE, 256, 0, stream>>>(src, dst, rowp, cursor, csrsrc, E);

    // ---- weight conversions (tiny) ----
    k_cvtB<<<(H * H + 255) / 256, 256, 0, stream>>>(W2, W2th, W2tl, H, H);
    k_cvtB<<<(H * L + 255) / 256, 256, 0, stream>>>(Wmu, Wmuth, Wmutl, H, L);
    k_cvtB<<<(H * L + 255) / 256, 256, 0, stream>>>(Wlv, Wlvth, Wlvtl, H, L);
    k_cvtB<<<(L * H + 255) / 256, 256, 0, stream>>>(W3, W3th, W3tl, L, H);
    k_cvtB<<<(H * V + 255) / 256, 256, 0, stream>>>(W4, W4th, W4tl, H, V);

    // ---- conv1: embW1 = emb @ W1 (tiny fp32), table aggregation -> h1 pair
    k_gemm_f32<<<dim3(V / 64, H / 64), 256, 0, stream>>>(emb, W1, embW1, V, F, H);
    k_agg_idx_pair<<<(N + 3) / 4, 256, 0, stream>>>(
        embW1, x, rowp, csrsrc, dinv, b1, pairH, pairL, N);

    // ---- conv2: hW2 = h1 @ W2 (MFMA, fp32 out), agg -> h2 pair ----
    k_gemm_mfma<false, false, false><<<dim3(gM, H / 64), 256, 0, stream>>>(
        pairH, pairL, W2th, W2tl, nullptr, bufA, nullptr, nullptr, N, H, H);
    k_agg_pair<<<(N + 3) / 4, 256, 0, stream>>>(
        bufA, rowp, csrsrc, dinv, b2, pairH, pairL, N);

    // ---- heads: mu, logvar (MFMA, fp32 out to d_out) ----
    k_gemm_mfma<false, true, false><<<dim3(gM, L / 64), 256, 0, stream>>>(
        pairH, pairL, Wmuth, Wmutl, bmu, mu, nullptr, nullptr, N, H, L);
    k_gemm_mfma<false, true, false><<<dim3(gM, L / 64), 256, 0, stream>>>(
        pairH, pairL, Wlvth, Wlvtl, blv, logvar, nullptr, nullptr, N, H, L);

    // ---- reparameterize -> z pair ----
    k_z<<<(N * L + 255) / 256, 256, 0, stream>>>(mu, logvar, eps, zh, zl, N * L);

    // ---- decode: t = relu(z@W3+b3) -> t pair; recon = t@W4+b4 ----
    k_gemm_mfma<true, true, true><<<dim3(gM, H / 64), 256, 0, stream>>>(
        zh, zl, W3th, W3tl, b3, nullptr, tH, tL, N, L, H);
    k_gemm_mfma<false, true, false><<<dim3(gM, V / 64), 256, 0, stream>>>(
        tH, tL, W4th, W4tl, b4, recon, nullptr, nullptr, N, H, V);

    // ---- capitalize head ----
    k_cap<<<(N + 3) / 4, 256, 0, stream>>>(zh, zl, Wcap, bcap, cap, N);
}

// Round 5
// 536.556 us; speedup vs baseline: 2.0906x; 1.0864x over previous
//
#include <hip/hip_runtime.h>
#include <math.h>

// ---------------------------------------------------------------------------
// GCN-VAE forward, round 5.
//  - conv2 reordered: A_hat(h1 @ W2) -> (A_hat h1) @ W2. h1 stored as plain
//    bf16; agg2 gathers 2B/feat (halved bytes vs R4's 405MB fetch).
//  - conv1 table (embW1) stored bf16 for the gather; agg1 emits bf16 h1.
//  - mu/logvar/z fused into ONE GEMM (Wmu|Wlv concat, BN=128): epilogue
//    computes z = mu + eps*exp(0.5*lv) in-register. k_z deleted.
// ---------------------------------------------------------------------------

typedef __attribute__((ext_vector_type(8))) short bf16x8;
typedef __attribute__((ext_vector_type(4))) float f32x4;

__device__ inline unsigned short f2bf(float x) {
    unsigned u = __float_as_uint(x);
    return (unsigned short)((u + 0x7FFFu + ((u >> 16) & 1u)) >> 16);
}
__device__ inline float bf2f(unsigned short h) {
    return __uint_as_float(((unsigned)h) << 16);
}

// ============================ CSR build ====================================
__global__ __launch_bounds__(256) void k_init(int* __restrict__ degint,
                                              int* __restrict__ cursor, int N) {
    int i = blockIdx.x * 256 + threadIdx.x;
    if (i < N) { degint[i] = 1; cursor[i] = 0; }   // 1 = self-loop
}

__global__ __launch_bounds__(256) void k_deg_count(const int* __restrict__ dst,
                                                   int* __restrict__ degint, int E) {
    int e = blockIdx.x * 256 + threadIdx.x;
    if (e < E) atomicAdd(&degint[dst[e]], 1);
}

__global__ __launch_bounds__(256) void k_dinv(const int* __restrict__ degint,
                                              float* __restrict__ dinv, int N) {
    int i = blockIdx.x * 256 + threadIdx.x;
    if (i < N) dinv[i] = rsqrtf((float)degint[i]);
}

#define SCAN_BLOCK 1024
__global__ __launch_bounds__(SCAN_BLOCK) void k_scan_local(
        const int* __restrict__ degint, int* __restrict__ row_ptr,
        int* __restrict__ bsum, int N) {
    __shared__ int s[SCAN_BLOCK];
    int gid = blockIdx.x * SCAN_BLOCK + threadIdx.x;
    int v = (gid < N) ? (degint[gid] - 1) : 0;
    s[threadIdx.x] = v;
    __syncthreads();
    for (int off = 1; off < SCAN_BLOCK; off <<= 1) {
        int t = (threadIdx.x >= off) ? s[threadIdx.x - off] : 0;
        __syncthreads();
        s[threadIdx.x] += t;
        __syncthreads();
    }
    if (gid < N) row_ptr[gid] = s[threadIdx.x] - v;          // exclusive
    if (threadIdx.x == SCAN_BLOCK - 1) bsum[blockIdx.x] = s[SCAN_BLOCK - 1];
}

__global__ void k_scan_bsum(int* __restrict__ bsum, int nb) {
    if (blockIdx.x == 0 && threadIdx.x == 0) {
        int acc = 0;
        for (int i = 0; i < nb; ++i) { int v = bsum[i]; bsum[i] = acc; acc += v; }
    }
}

__global__ __launch_bounds__(256) void k_scan_add(int* __restrict__ row_ptr,
                                                  const int* __restrict__ bsum,
                                                  int N, int E) {
    int gid = blockIdx.x * 256 + threadIdx.x;
    if (gid < N) row_ptr[gid] += bsum[gid / SCAN_BLOCK];
    if (gid == 0) row_ptr[N] = E;
}

__global__ __launch_bounds__(256) void k_csr_fill(
        const int* __restrict__ src, const int* __restrict__ dst,
        const int* __restrict__ row_ptr, int* __restrict__ cursor,
        int* __restrict__ csr_src, int E) {
    int e = blockIdx.x * 256 + threadIdx.x;
    if (e < E) {
        int d = dst[e];
        int pos = atomicAdd(&cursor[d], 1);
        csr_src[row_ptr[d] + pos] = src[e];
    }
}

// ============ weight transpose + hi/lo split: B[K,N] -> Bt{h,l}[N,K] =======
__global__ __launch_bounds__(256) void k_cvtB(
        const float* __restrict__ B, unsigned short* __restrict__ Bth,
        unsigned short* __restrict__ Btl, int K, int Ncol) {
    int i = blockIdx.x * 256 + threadIdx.x;
    if (i >= K * Ncol) return;
    int k = i / Ncol, n = i - k * Ncol;
    float v = B[i];
    unsigned short h = f2bf(v);
    Bth[(long)n * K + k] = h;
    Btl[(long)n * K + k] = f2bf(v - bf2f(h));
}

// ---- fp32 -> bf16 elementwise (for embW1 table) ---------------------------
__global__ __launch_bounds__(256) void k_cvt_tab(
        const float* __restrict__ src, unsigned short* __restrict__ dst, int n) {
    int i = blockIdx.x * 256 + threadIdx.x;
    if (i < n) dst[i] = f2bf(src[i]);
}

// ================= small fp32 GEMM (embW1 = emb @ W1 only) =================
__global__ __launch_bounds__(256) void k_gemm_f32(
        const float* __restrict__ A, const float* __restrict__ B,
        float* __restrict__ C, int M, int K, int Ncol) {
    constexpr int BM = 64, BN = 64, BK = 16;
    __shared__ float As[BK][BM];
    __shared__ float Bs[BK][BN];
    const int tid = threadIdx.x;
    const int tx = tid & 15, ty = tid >> 4;
    const int rowBase = blockIdx.x * BM;
    const int colBase = blockIdx.y * BN;
    const int lr = tid >> 2, lc4 = tid & 3;
    const int br = tid >> 4, bc4 = tid & 15;
    const int arow = rowBase + lr;
    const int K4 = K >> 2, N4 = Ncol >> 2;
    const float4* A4 = (const float4*)A;
    const float4* B4 = (const float4*)B;
    float acc[4][4] = {{0.f}};
    for (int k0 = 0; k0 < K; k0 += BK) {
        float4 av = make_float4(0.f, 0.f, 0.f, 0.f);
        if (arow < M) av = A4[(long)arow * K4 + (k0 >> 2) + lc4];
        As[lc4 * 4 + 0][lr] = av.x;
        As[lc4 * 4 + 1][lr] = av.y;
        As[lc4 * 4 + 2][lr] = av.z;
        As[lc4 * 4 + 3][lr] = av.w;
        float4 bv = B4[(long)(k0 + br) * N4 + (colBase >> 2) + bc4];
        *(float4*)&Bs[br][bc4 * 4] = bv;
        __syncthreads();
#pragma unroll
        for (int k = 0; k < BK; ++k) {
            float4 a4v = *(const float4*)&As[k][ty * 4];
            float4 b4v = *(const float4*)&Bs[k][tx * 4];
            float aa[4] = {a4v.x, a4v.y, a4v.z, a4v.w};
            float bb[4] = {b4v.x, b4v.y, b4v.z, b4v.w};
#pragma unroll
            for (int i = 0; i < 4; ++i)
#pragma unroll
                for (int j = 0; j < 4; ++j)
                    acc[i][j] = fmaf(aa[i], bb[j], acc[i][j]);
        }
        __syncthreads();
    }
#pragma unroll
    for (int i = 0; i < 4; ++i) {
        int row = rowBase + ty * 4 + i;
        if (row < M) {
            float4 o = make_float4(acc[i][0], acc[i][1], acc[i][2], acc[i][3]);
            ((float4*)C)[(long)row * N4 + (colBase >> 2) + tx] = o;
        }
    }
}

// ================= MFMA GEMM with bf16 hi/lo split (R4, proven) ============
// BM=128 BN=64 BK=32, 256 threads = 4 waves.
template<bool RELU, bool BIAS, bool OUTPAIR>
__global__ __launch_bounds__(256) void k_gemm_mfma(
        const unsigned short* __restrict__ Ah, const unsigned short* __restrict__ Al,
        const unsigned short* __restrict__ Bth, const unsigned short* __restrict__ Btl,
        const float* __restrict__ bias, float* __restrict__ Cf,
        unsigned short* __restrict__ Ch, unsigned short* __restrict__ Cl,
        int M, int K, int Ncol) {
    __shared__ unsigned short Ash[128][40];
    __shared__ unsigned short Asl[128][40];
    __shared__ unsigned short Bsh[64][40];
    __shared__ unsigned short Bsl[64][40];
    const int tid = threadIdx.x;
    const int lane = tid & 63, w = tid >> 6;
    const int fr = lane & 15, quad = lane >> 4;
    const int wm0 = w * 32;
    const int rowBase = blockIdx.x * 128;
    const int colBase = blockIdx.y * 64;

    const int arow = tid >> 1;
    const int ahalf = (tid & 1) << 4;
    int agrow = rowBase + arow; if (agrow >= M) agrow = M - 1;
    const long abase = (long)agrow * K + ahalf;
    const int bt = tid & 127;
    const int brow = bt >> 1;
    const int bhalf = (bt & 1) << 4;
    const long bbase = (long)(colBase + brow) * K + bhalf;
    const unsigned short* Bsrc = (tid < 128) ? Bth : Btl;
    unsigned short* Bdst = (tid < 128) ? &Bsh[brow][bhalf] : &Bsl[brow][bhalf];

    f32x4 acc[2][4];
#pragma unroll
    for (int i = 0; i < 2; ++i)
#pragma unroll
        for (int j = 0; j < 4; ++j) acc[i][j] = (f32x4){0.f, 0.f, 0.f, 0.f};

    for (int k0 = 0; k0 < K; k0 += 32) {
        *(bf16x8*)&Ash[arow][ahalf]     = *(const bf16x8*)&Ah[abase + k0];
        *(bf16x8*)&Ash[arow][ahalf + 8] = *(const bf16x8*)&Ah[abase + k0 + 8];
        *(bf16x8*)&Asl[arow][ahalf]     = *(const bf16x8*)&Al[abase + k0];
        *(bf16x8*)&Asl[arow][ahalf + 8] = *(const bf16x8*)&Al[abase + k0 + 8];
        *(bf16x8*)Bdst       = *(const bf16x8*)&Bsrc[bbase + k0];
        *(bf16x8*)(Bdst + 8) = *(const bf16x8*)&Bsrc[bbase + k0 + 8];
        __syncthreads();
        bf16x8 ahf[2], alf[2], bhf[4], blf[4];
#pragma unroll
        for (int i = 0; i < 2; ++i) {
            ahf[i] = *(const bf16x8*)&Ash[wm0 + i * 16 + fr][quad * 8];
            alf[i] = *(const bf16x8*)&Asl[wm0 + i * 16 + fr][quad * 8];
        }
#pragma unroll
        for (int j = 0; j < 4; ++j) {
            bhf[j] = *(const bf16x8*)&Bsh[j * 16 + fr][quad * 8];
            blf[j] = *(const bf16x8*)&Bsl[j * 16 + fr][quad * 8];
        }
#pragma unroll
        for (int i = 0; i < 2; ++i)
#pragma unroll
            for (int j = 0; j < 4; ++j) {
                acc[i][j] = __builtin_amdgcn_mfma_f32_16x16x32_bf16(
                    ahf[i], bhf[j], acc[i][j], 0, 0, 0);
                acc[i][j] = __builtin_amdgcn_mfma_f32_16x16x32_bf16(
                    ahf[i], blf[j], acc[i][j], 0, 0, 0);
                acc[i][j] = __builtin_amdgcn_mfma_f32_16x16x32_bf16(
                    alf[i], bhf[j], acc[i][j], 0, 0, 0);
            }
        __syncthreads();
    }

#pragma unroll
    for (int i = 0; i < 2; ++i) {
        const int rowb = rowBase + wm0 + i * 16 + quad * 4;
#pragma unroll
        for (int j = 0; j < 4; ++j) {
            const int col = colBase + j * 16 + fr;
            const float bv = BIAS ? bias[col] : 0.f;
#pragma unroll
            for (int r = 0; r < 4; ++r) {
                const int row = rowb + r;
                if (row < M) {
                    float v = acc[i][j][r] + bv;
                    if (RELU) v = fmaxf(v, 0.f);
                    const long o = (long)row * Ncol + col;
                    if (OUTPAIR) {
                        unsigned short h = f2bf(v);
                        Ch[o] = h;
                        Cl[o] = f2bf(v - bf2f(h));
                    } else {
                        Cf[o] = v;
                    }
                }
            }
        }
    }
}

// ============== fused heads GEMM: [mu|lv] = h2 @ (Wmu|Wlv), + z ============
// BM=64, BN=128, BK=32, K=256. 4 waves, wave w owns rows w*16..w*16+16.
// Thread holds mu col c (j<4) and lv col c (j+4) for same rows -> fuse z.
__global__ __launch_bounds__(256) void k_gemm_heads(
        const unsigned short* __restrict__ Ah, const unsigned short* __restrict__ Al,
        const unsigned short* __restrict__ Bth, const unsigned short* __restrict__ Btl,
        const float* __restrict__ bmu, const float* __restrict__ blv,
        const float* __restrict__ eps, float* __restrict__ mu,
        float* __restrict__ lv, unsigned short* __restrict__ Zh,
        unsigned short* __restrict__ Zl, int M) {
    constexpr int K = 256;
    __shared__ unsigned short Ash[64][40];
    __shared__ unsigned short Asl[64][40];
    __shared__ unsigned short Bsh[128][40];
    __shared__ unsigned short Bsl[128][40];
    const int tid = threadIdx.x;
    const int lane = tid & 63, w = tid >> 6;
    const int fr = lane & 15, quad = lane >> 4;
    const int wm0 = w * 16;
    const int rowBase = blockIdx.x * 64;

    const int arow = tid >> 2;                 // 0..63
    const int aseg = (tid & 3) << 3;           // 0,8,16,24
    int agrow = rowBase + arow; if (agrow >= M) agrow = M - 1;
    const long abase = (long)agrow * K + aseg;
    const int brow = tid >> 1;                 // 0..127
    const int bseg = (tid & 1) << 4;           // 0 | 16
    const long bbase = (long)brow * K + bseg;

    f32x4 acc[8];
#pragma unroll
    for (int j = 0; j < 8; ++j) acc[j] = (f32x4){0.f, 0.f, 0.f, 0.f};

    for (int k0 = 0; k0 < K; k0 += 32) {
        *(bf16x8*)&Ash[arow][aseg] = *(const bf16x8*)&Ah[abase + k0];
        *(bf16x8*)&Asl[arow][aseg] = *(const bf16x8*)&Al[abase + k0];
        *(bf16x8*)&Bsh[brow][bseg]     = *(const bf16x8*)&Bth[bbase + k0];
        *(bf16x8*)&Bsh[brow][bseg + 8] = *(const bf16x8*)&Bth[bbase + k0 + 8];
        *(bf16x8*)&Bsl[brow][bseg]     = *(const bf16x8*)&Btl[bbase + k0];
        *(bf16x8*)&Bsl[brow][bseg + 8] = *(const bf16x8*)&Btl[bbase + k0 + 8];
        __syncthreads();
        bf16x8 ahf = *(const bf16x8*)&Ash[wm0 + fr][quad * 8];
        bf16x8 alf = *(const bf16x8*)&Asl[wm0 + fr][quad * 8];
#pragma unroll
        for (int j = 0; j < 8; ++j) {
            bf16x8 bhf = *(const bf16x8*)&Bsh[j * 16 + fr][quad * 8];
            bf16x8 blf = *(const bf16x8*)&Bsl[j * 16 + fr][quad * 8];
            acc[j] = __builtin_amdgcn_mfma_f32_16x16x32_bf16(ahf, bhf, acc[j], 0, 0, 0);
            acc[j] = __builtin_amdgcn_mfma_f32_16x16x32_bf16(ahf, blf, acc[j], 0, 0, 0);
            acc[j] = __builtin_amdgcn_mfma_f32_16x16x32_bf16(alf, bhf, acc[j], 0, 0, 0);
        }
        __syncthreads();
    }

#pragma unroll
    for (int j = 0; j < 4; ++j) {
        const int c = j * 16 + fr;             // latent index 0..63
        const float bm = bmu[c], bl = blv[c];
#pragma unroll
        for (int r = 0; r < 4; ++r) {
            const int row = rowBase + wm0 + quad * 4 + r;
            if (row < M) {
                const long o = (long)row * 64 + c;
                float mv = acc[j][r] + bm;
                float lvv = acc[j + 4][r] + bl;
                mu[o] = mv;
                lv[o] = lvv;
                float zz = fmaf(eps[o], expf(0.5f * lvv), mv);
                unsigned short h = f2bf(zz);
                Zh[o] = h;
                Zl[o] = f2bf(zz - bf2f(h));
            }
        }
    }
}

// ========= conv1 aggregation from bf16 table -> h1 bf16 ====================
// h1[i] = relu(b1 + di^2*T[x[i]] + sum_s dinv[s]*di*T[x[s]]); wave per node,
// lane covers 4 feats (ushort4 = 8B).
__global__ __launch_bounds__(256) void k_agg_tab(
        const unsigned short* __restrict__ tab, const int* __restrict__ x,
        const int* __restrict__ row_ptr, const int* __restrict__ csr_src,
        const float* __restrict__ dinv, const float* __restrict__ bias,
        unsigned short* __restrict__ h1, int N) {
    const int wave = threadIdx.x >> 6;
    const int lane = threadIdx.x & 63;
    const int node = blockIdx.x * 4 + wave;
    if (node >= N) return;
    const ushort4* t4 = (const ushort4*)tab;   // row = 64 ushort4
    const float di = dinv[node];
    const float selfw = di * di;
    ushort4 a = t4[(long)x[node] * 64 + lane];
    float ax = bf2f(a.x) * selfw, ay = bf2f(a.y) * selfw;
    float az = bf2f(a.z) * selfw, aw = bf2f(a.w) * selfw;
    const int beg = row_ptr[node], end = row_ptr[node + 1];
    for (int e = beg; e < end; ++e) {
        int s = csr_src[e];
        float wgt = dinv[s] * di;
        ushort4 v = t4[(long)x[s] * 64 + lane];
        ax = fmaf(bf2f(v.x), wgt, ax); ay = fmaf(bf2f(v.y), wgt, ay);
        az = fmaf(bf2f(v.z), wgt, az); aw = fmaf(bf2f(v.w), wgt, aw);
    }
    float4 b = ((const float4*)bias)[lane];
    ax = fmaxf(ax + b.x, 0.f); ay = fmaxf(ay + b.y, 0.f);
    az = fmaxf(az + b.z, 0.f); aw = fmaxf(aw + b.w, 0.f);
    ushort4 o;
    o.x = f2bf(ax); o.y = f2bf(ay); o.z = f2bf(az); o.w = f2bf(aw);
    ((ushort4*)h1)[(long)node * 64 + lane] = o;
}

// ========= conv2 aggregation: a2 = A_hat h1 (bf16 gather, pair out) ========
// NO bias/relu (moved into GEMM2). 2-edge unroll for MLP.
__global__ __launch_bounds__(256) void k_agg_nb(
        const unsigned short* __restrict__ h1, const int* __restrict__ row_ptr,
        const int* __restrict__ csr_src, const float* __restrict__ dinv,
        unsigned short* __restrict__ Oh, unsigned short* __restrict__ Ol, int N) {
    const int wave = threadIdx.x >> 6;
    const int lane = threadIdx.x & 63;
    const int node = blockIdx.x * 4 + wave;
    if (node >= N) return;
    const ushort4* h4 = (const ushort4*)h1;
    const float di = dinv[node];
    const float selfw = di * di;
    ushort4 a = h4[(long)node * 64 + lane];
    float ax = bf2f(a.x) * selfw, ay = bf2f(a.y) * selfw;
    float az = bf2f(a.z) * selfw, aw = bf2f(a.w) * selfw;
    const int beg = row_ptr[node], end = row_ptr[node + 1];
    int e = beg;
    for (; e + 1 < end; e += 2) {
        int s0 = csr_src[e], s1 = csr_src[e + 1];
        float w0 = dinv[s0] * di, w1 = dinv[s1] * di;
        ushort4 v0 = h4[(long)s0 * 64 + lane];
        ushort4 v1 = h4[(long)s1 * 64 + lane];
        ax = fmaf(bf2f(v0.x), w0, ax); ay = fmaf(bf2f(v0.y), w0, ay);
        az = fmaf(bf2f(v0.z), w0, az); aw = fmaf(bf2f(v0.w), w0, aw);
        ax = fmaf(bf2f(v1.x), w1, ax); ay = fmaf(bf2f(v1.y), w1, ay);
        az = fmaf(bf2f(v1.z), w1, az); aw = fmaf(bf2f(v1.w), w1, aw);
    }
    if (e < end) {
        int s = csr_src[e];
        float wgt = dinv[s] * di;
        ushort4 v = h4[(long)s * 64 + lane];
        ax = fmaf(bf2f(v.x), wgt, ax); ay = fmaf(bf2f(v.y), wgt, ay);
        az = fmaf(bf2f(v.z), wgt, az); aw = fmaf(bf2f(v.w), wgt, aw);
    }
    const long base = (long)node * 64 + lane;
    ushort4 hh, ll;
    hh.x = f2bf(ax); ll.x = f2bf(ax - bf2f(hh.x));
    hh.y = f2bf(ay); ll.y = f2bf(ay - bf2f(hh.y));
    hh.z = f2bf(az); ll.z = f2bf(az - bf2f(hh.z));
    hh.w = f2bf(aw); ll.w = f2bf(aw - bf2f(hh.w));
    ((ushort4*)Oh)[base] = hh;
    ((ushort4*)Ol)[base] = ll;
}

// ---- capitalize = sigmoid(z @ Wcap + bcap) --------------------------------
__global__ __launch_bounds__(256) void k_cap(
        const unsigned short* __restrict__ Zh, const unsigned short* __restrict__ Zl,
        const float* __restrict__ Wcap, const float* __restrict__ bcap,
        float* __restrict__ out, int N) {
    const int wave = threadIdx.x >> 6;
    const int lane = threadIdx.x & 63;
    const int node = blockIdx.x * 4 + wave;
    if (node >= N) return;
    long idx = (long)node * 64 + lane;
    float v = (bf2f(Zh[idx]) + bf2f(Zl[idx])) * Wcap[lane];
    for (int off = 32; off; off >>= 1) v += __shfl_down(v, off, 64);
    if (lane == 0) out[node] = 1.f / (1.f + expf(-(v + bcap[0])));
}

extern "C" void kernel_launch(void* const* d_in, const int* in_sizes, int n_in,
                              void* d_out, int out_size, void* d_ws, size_t ws_size,
                              hipStream_t stream) {
    const int*   x    = (const int*)d_in[0];
    const int*   ei   = (const int*)d_in[1];
    const float* eps  = (const float*)d_in[2];
    const float* emb  = (const float*)d_in[3];
    const float* W1   = (const float*)d_in[4];
    const float* b1   = (const float*)d_in[5];
    const float* W2   = (const float*)d_in[6];
    const float* b2   = (const float*)d_in[7];
    const float* Wmu  = (const float*)d_in[8];
    const float* bmu  = (const float*)d_in[9];
    const float* Wlv  = (const float*)d_in[10];
    const float* blv  = (const float*)d_in[11];
    const float* W3   = (const float*)d_in[12];
    const float* b3   = (const float*)d_in[13];
    const float* W4   = (const float*)d_in[14];
    const float* b4   = (const float*)d_in[15];
    const float* Wcap = (const float*)d_in[16];
    const float* bcap = (const float*)d_in[17];

    const int N = in_sizes[0];
    const int E = in_sizes[1] / 2;
    const int H = in_sizes[5];            // 256
    const int L = in_sizes[9];            // 64
    const int V = in_sizes[15];           // 128
    const int F = in_sizes[4] / H;        // 128

    const int* src = ei;
    const int* dst = ei + E;

    // ---- workspace carve-up ----
    char* w = (char*)d_ws;
    unsigned short* h1b  = (unsigned short*)w; w += (size_t)N * H * 2;  // bf16 h1
    unsigned short* a2h  = (unsigned short*)w; w += (size_t)N * H * 2;  // a2 / t hi
    unsigned short* a2l  = (unsigned short*)w; w += (size_t)N * H * 2;  // a2 / t lo
    unsigned short* pairH = (unsigned short*)w; w += (size_t)N * H * 2; // h2 hi
    unsigned short* pairL = (unsigned short*)w; w += (size_t)N * H * 2; // h2 lo
    unsigned short* zh   = (unsigned short*)w; w += (size_t)N * L * 2;
    unsigned short* zl   = (unsigned short*)w; w += (size_t)N * L * 2;
    int*   degint = (int*)w;   w += (size_t)N * 4;
    int*   rowp   = (int*)w;   w += (size_t)(N + 1) * 4;
    int*   cursor = (int*)w;   w += (size_t)N * 4;
    float* dinv   = (float*)w; w += (size_t)N * 4;
    int*   bsum   = (int*)w;   w += 256 * 4;
    int*   csrsrc = (int*)w;   w += (size_t)E * 4;
    float* embW1  = (float*)w; w += (size_t)V * H * 4;
    unsigned short* tabH  = (unsigned short*)w; w += (size_t)V * H * 2;
    unsigned short* W2th  = (unsigned short*)w; w += (size_t)H * H * 2;
    unsigned short* W2tl  = (unsigned short*)w; w += (size_t)H * H * 2;
    unsigned short* Wmlth = (unsigned short*)w; w += (size_t)H * 2 * L * 2; // [128][256]
    unsigned short* Wmltl = (unsigned short*)w; w += (size_t)H * 2 * L * 2;
    unsigned short* W3th  = (unsigned short*)w; w += (size_t)L * H * 2;
    unsigned short* W3tl  = (unsigned short*)w; w += (size_t)L * H * 2;
    unsigned short* W4th  = (unsigned short*)w; w += (size_t)H * V * 2;
    unsigned short* W4tl  = (unsigned short*)w; w += (size_t)H * V * 2;

    unsigned short* tH = a2h;   // a2 dead after GEMM2
    unsigned short* tL = a2l;

    float* outp    = (float*)d_out;
    float* recon   = outp;                               // [N, V]
    float* cap     = outp + (size_t)N * V;               // [N, 1]
    float* mu      = outp + (size_t)N * V + N;           // [N, L]
    float* logvar  = mu + (size_t)N * L;                 // [N, L]

    const int nN  = (N + 255) / 256;
    const int nE  = (E + 255) / 256;
    const int nSc = (N + SCAN_BLOCK - 1) / SCAN_BLOCK;
    const int gM128 = (N + 127) / 128;
    const int gM64  = (N + 63) / 64;

    // ---- degree / dinv / CSR ----
    k_init<<<nN, 256, 0, stream>>>(degint, cursor, N);
    k_deg_count<<<nE, 256, 0, stream>>>(dst, degint, E);
    k_dinv<<<nN, 256, 0, stream>>>(degint, dinv, N);
    k_scan_local<<<nSc, SCAN_BLOCK, 0, stream>>>(degint, rowp, bsum, N);
    k_scan_bsum<<<1, 64, 0, stream>>>(bsum, nSc);
    k_scan_add<<<nN, 256, 0, stream>>>(rowp, bsum, N, E);
    k_csr_fill<<<nE, 256, 0, stream>>>(src, dst, rowp, cursor, csrsrc, E);

    // ---- weight conversions (tiny) ----
    k_cvtB<<<(H * H + 255) / 256, 256, 0, stream>>>(W2, W2th, W2tl, H, H);
    k_cvtB<<<(H * L + 255) / 256, 256, 0, stream>>>(Wmu, Wmlth, Wmltl, H, L);
    k_cvtB<<<(H * L + 255) / 256, 256, 0, stream>>>(
        Wlv, Wmlth + (size_t)L * H, Wmltl + (size_t)L * H, H, L);
    k_cvtB<<<(L * H + 255) / 256, 256, 0, stream>>>(W3, W3th, W3tl, L, H);
    k_cvtB<<<(H * V + 255) / 256, 256, 0, stream>>>(W4, W4th, W4tl, H, V);

    // ---- conv1: embW1 = emb @ W1 (fp32), -> bf16 table, agg -> h1 bf16 ----
    k_gemm_f32<<<dim3(V / 64, H / 64), 256, 0, stream>>>(emb, W1, embW1, V, F, H);
    k_cvt_tab<<<(V * H + 255) / 256, 256, 0, stream>>>(embW1, tabH, V * H);
    k_agg_tab<<<(N + 3) / 4, 256, 0, stream>>>(
        tabH, x, rowp, csrsrc, dinv, b1, h1b, N);

    // ---- conv2 (reordered): a2 = A_hat h1; h2 = relu(a2 @ W2 + b2) --------
    k_agg_nb<<<(N + 3) / 4, 256, 0, stream>>>(
        h1b, rowp, csrsrc, dinv, a2h, a2l, N);
    k_gemm_mfma<true, true, true><<<dim3(gM128, H / 64), 256, 0, stream>>>(
        a2h, a2l, W2th, W2tl, b2, nullptr, pairH, pairL, N, H, H);

    // ---- fused heads: mu, logvar, z ----
    k_gemm_heads<<<gM64, 256, 0, stream>>>(
        pairH, pairL, Wmlth, Wmltl, bmu, blv, eps, mu, logvar, zh, zl, N);

    // ---- decode: t = relu(z@W3+b3); recon = t@W4+b4 ----
    k_gemm_mfma<true, true, true><<<dim3(gM128, H / 64), 256, 0, stream>>>(
        zh, zl, W3th, W3tl, b3, nullptr, tH, tL, N, L, H);
    k_gemm_mfma<false, true, false><<<dim3(gM128, V / 64), 256, 0, stream>>>(
        tH, tL, W4th, W4tl, b4, recon, nullptr, nullptr, N, H, V);

    // ---- capitalize head ----
    k_cap<<<(N + 3) / 4, 256, 0, stream>>>(zh, zl, Wcap, bcap, cap, N);
}

// Round 6
// 469.727 us; speedup vs baseline: 2.3880x; 1.1423x over previous
//
#include <hip/hip_runtime.h>
#include <math.h>

// ---------------------------------------------------------------------------
// GCN-VAE forward, round 6.
//  - 2-MFMA split GEMMs: activations single bf16, weights hi/lo bf16 pair
//    (error ~0.4% of activation << bf16 output-compare floor).
//  - all intermediate activations single bf16 (a2/h2/z/t): halves agg_nb
//    write and every GEMM A-read.
//  - cap head fused into heads-GEMM epilogue (shfl_xor reduce over fr lanes).
// ---------------------------------------------------------------------------

typedef __attribute__((ext_vector_type(8))) short bf16x8;
typedef __attribute__((ext_vector_type(4))) float f32x4;

__device__ inline unsigned short f2bf(float x) {
    unsigned u = __float_as_uint(x);
    return (unsigned short)((u + 0x7FFFu + ((u >> 16) & 1u)) >> 16);
}
__device__ inline float bf2f(unsigned short h) {
    return __uint_as_float(((unsigned)h) << 16);
}

// ============================ CSR build ====================================
__global__ __launch_bounds__(256) void k_init(int* __restrict__ degint,
                                              int* __restrict__ cursor, int N) {
    int i = blockIdx.x * 256 + threadIdx.x;
    if (i < N) { degint[i] = 1; cursor[i] = 0; }   // 1 = self-loop
}

__global__ __launch_bounds__(256) void k_deg_count(const int* __restrict__ dst,
                                                   int* __restrict__ degint, int E) {
    int e = blockIdx.x * 256 + threadIdx.x;
    if (e < E) atomicAdd(&degint[dst[e]], 1);
}

__global__ __launch_bounds__(256) void k_dinv(const int* __restrict__ degint,
                                              float* __restrict__ dinv, int N) {
    int i = blockIdx.x * 256 + threadIdx.x;
    if (i < N) dinv[i] = rsqrtf((float)degint[i]);
}

#define SCAN_BLOCK 1024
__global__ __launch_bounds__(SCAN_BLOCK) void k_scan_local(
        const int* __restrict__ degint, int* __restrict__ row_ptr,
        int* __restrict__ bsum, int N) {
    __shared__ int s[SCAN_BLOCK];
    int gid = blockIdx.x * SCAN_BLOCK + threadIdx.x;
    int v = (gid < N) ? (degint[gid] - 1) : 0;
    s[threadIdx.x] = v;
    __syncthreads();
    for (int off = 1; off < SCAN_BLOCK; off <<= 1) {
        int t = (threadIdx.x >= off) ? s[threadIdx.x - off] : 0;
        __syncthreads();
        s[threadIdx.x] += t;
        __syncthreads();
    }
    if (gid < N) row_ptr[gid] = s[threadIdx.x] - v;          // exclusive
    if (threadIdx.x == SCAN_BLOCK - 1) bsum[blockIdx.x] = s[SCAN_BLOCK - 1];
}

__global__ void k_scan_bsum(int* __restrict__ bsum, int nb) {
    if (blockIdx.x == 0 && threadIdx.x == 0) {
        int acc = 0;
        for (int i = 0; i < nb; ++i) { int v = bsum[i]; bsum[i] = acc; acc += v; }
    }
}

__global__ __launch_bounds__(256) void k_scan_add(int* __restrict__ row_ptr,
                                                  const int* __restrict__ bsum,
                                                  int N, int E) {
    int gid = blockIdx.x * 256 + threadIdx.x;
    if (gid < N) row_ptr[gid] += bsum[gid / SCAN_BLOCK];
    if (gid == 0) row_ptr[N] = E;
}

__global__ __launch_bounds__(256) void k_csr_fill(
        const int* __restrict__ src, const int* __restrict__ dst,
        const int* __restrict__ row_ptr, int* __restrict__ cursor,
        int* __restrict__ csr_src, int E) {
    int e = blockIdx.x * 256 + threadIdx.x;
    if (e < E) {
        int d = dst[e];
        int pos = atomicAdd(&cursor[d], 1);
        csr_src[row_ptr[d] + pos] = src[e];
    }
}

// ============ weight transpose + hi/lo split: B[K,N] -> Bt{h,l}[N,K] =======
__global__ __launch_bounds__(256) void k_cvtB(
        const float* __restrict__ B, unsigned short* __restrict__ Bth,
        unsigned short* __restrict__ Btl, int K, int Ncol) {
    int i = blockIdx.x * 256 + threadIdx.x;
    if (i >= K * Ncol) return;
    int k = i / Ncol, n = i - k * Ncol;
    float v = B[i];
    unsigned short h = f2bf(v);
    Bth[(long)n * K + k] = h;
    Btl[(long)n * K + k] = f2bf(v - bf2f(h));
}

// ---- fp32 -> bf16 elementwise (for embW1 table) ---------------------------
__global__ __launch_bounds__(256) void k_cvt_tab(
        const float* __restrict__ src, unsigned short* __restrict__ dst, int n) {
    int i = blockIdx.x * 256 + threadIdx.x;
    if (i < n) dst[i] = f2bf(src[i]);
}

// ================= small fp32 GEMM (embW1 = emb @ W1 only) =================
__global__ __launch_bounds__(256) void k_gemm_f32(
        const float* __restrict__ A, const float* __restrict__ B,
        float* __restrict__ C, int M, int K, int Ncol) {
    constexpr int BM = 64, BN = 64, BK = 16;
    __shared__ float As[BK][BM];
    __shared__ float Bs[BK][BN];
    const int tid = threadIdx.x;
    const int tx = tid & 15, ty = tid >> 4;
    const int rowBase = blockIdx.x * BM;
    const int colBase = blockIdx.y * BN;
    const int lr = tid >> 2, lc4 = tid & 3;
    const int br = tid >> 4, bc4 = tid & 15;
    const int arow = rowBase + lr;
    const int K4 = K >> 2, N4 = Ncol >> 2;
    const float4* A4 = (const float4*)A;
    const float4* B4 = (const float4*)B;
    float acc[4][4] = {{0.f}};
    for (int k0 = 0; k0 < K; k0 += BK) {
        float4 av = make_float4(0.f, 0.f, 0.f, 0.f);
        if (arow < M) av = A4[(long)arow * K4 + (k0 >> 2) + lc4];
        As[lc4 * 4 + 0][lr] = av.x;
        As[lc4 * 4 + 1][lr] = av.y;
        As[lc4 * 4 + 2][lr] = av.z;
        As[lc4 * 4 + 3][lr] = av.w;
        float4 bv = B4[(long)(k0 + br) * N4 + (colBase >> 2) + bc4];
        *(float4*)&Bs[br][bc4 * 4] = bv;
        __syncthreads();
#pragma unroll
        for (int k = 0; k < BK; ++k) {
            float4 a4v = *(const float4*)&As[k][ty * 4];
            float4 b4v = *(const float4*)&Bs[k][tx * 4];
            float aa[4] = {a4v.x, a4v.y, a4v.z, a4v.w};
            float bb[4] = {b4v.x, b4v.y, b4v.z, b4v.w};
#pragma unroll
            for (int i = 0; i < 4; ++i)
#pragma unroll
                for (int j = 0; j < 4; ++j)
                    acc[i][j] = fmaf(aa[i], bb[j], acc[i][j]);
        }
        __syncthreads();
    }
#pragma unroll
    for (int i = 0; i < 4; ++i) {
        int row = rowBase + ty * 4 + i;
        if (row < M) {
            float4 o = make_float4(acc[i][0], acc[i][1], acc[i][2], acc[i][3]);
            ((float4*)C)[(long)row * N4 + (colBase >> 2) + tx] = o;
        }
    }
}

// ====== MFMA GEMM, 2-term split: C = A(bf16) @ (Bh+Bl), BM=128 BN=64 BK=32 =
// A bf16 [M,K] row-major; B pair [Ncol,K]. 256 thr = 4 waves; wave w owns
// rows [w*32, w*32+32).
template<bool RELU, bool BIAS, bool OUTBF>
__global__ __launch_bounds__(256) void k_gemm_mfma(
        const unsigned short* __restrict__ A,
        const unsigned short* __restrict__ Bth, const unsigned short* __restrict__ Btl,
        const float* __restrict__ bias, float* __restrict__ Cf,
        unsigned short* __restrict__ Cb, int M, int K, int Ncol) {
    __shared__ unsigned short Ash[128][40];   // 80B rows: b128 2-way (free)
    __shared__ unsigned short Bsh[64][40];
    __shared__ unsigned short Bsl[64][40];
    const int tid = threadIdx.x;
    const int lane = tid & 63, w = tid >> 6;
    const int fr = lane & 15, quad = lane >> 4;
    const int wm0 = w * 32;
    const int rowBase = blockIdx.x * 128;
    const int colBase = blockIdx.y * 64;

    const int arow = tid >> 1;                 // 0..127
    const int ahalf = (tid & 1) << 4;          // 0 | 16 shorts
    int agrow = rowBase + arow; if (agrow >= M) agrow = M - 1;
    const long abase = (long)agrow * K + ahalf;
    const int bt = tid & 127;
    const int brow = bt >> 1;                  // 0..63
    const int bhalf = (bt & 1) << 4;
    const long bbase = (long)(colBase + brow) * K + bhalf;
    const unsigned short* Bsrc = (tid < 128) ? Bth : Btl;
    unsigned short* Bdst = (tid < 128) ? &Bsh[brow][bhalf] : &Bsl[brow][bhalf];

    f32x4 acc[2][4];
#pragma unroll
    for (int i = 0; i < 2; ++i)
#pragma unroll
        for (int j = 0; j < 4; ++j) acc[i][j] = (f32x4){0.f, 0.f, 0.f, 0.f};

    for (int k0 = 0; k0 < K; k0 += 32) {
        *(bf16x8*)&Ash[arow][ahalf]     = *(const bf16x8*)&A[abase + k0];
        *(bf16x8*)&Ash[arow][ahalf + 8] = *(const bf16x8*)&A[abase + k0 + 8];
        *(bf16x8*)Bdst       = *(const bf16x8*)&Bsrc[bbase + k0];
        *(bf16x8*)(Bdst + 8) = *(const bf16x8*)&Bsrc[bbase + k0 + 8];
        __syncthreads();
        bf16x8 ahf[2], bhf[4], blf[4];
#pragma unroll
        for (int i = 0; i < 2; ++i)
            ahf[i] = *(const bf16x8*)&Ash[wm0 + i * 16 + fr][quad * 8];
#pragma unroll
        for (int j = 0; j < 4; ++j) {
            bhf[j] = *(const bf16x8*)&Bsh[j * 16 + fr][quad * 8];
            blf[j] = *(const bf16x8*)&Bsl[j * 16 + fr][quad * 8];
        }
#pragma unroll
        for (int i = 0; i < 2; ++i)
#pragma unroll
            for (int j = 0; j < 4; ++j) {
                acc[i][j] = __builtin_amdgcn_mfma_f32_16x16x32_bf16(
                    ahf[i], bhf[j], acc[i][j], 0, 0, 0);
                acc[i][j] = __builtin_amdgcn_mfma_f32_16x16x32_bf16(
                    ahf[i], blf[j], acc[i][j], 0, 0, 0);
            }
        __syncthreads();
    }

    // epilogue: C layout col=lane&15, row=quad*4+reg
#pragma unroll
    for (int i = 0; i < 2; ++i) {
        const int rowb = rowBase + wm0 + i * 16 + quad * 4;
#pragma unroll
        for (int j = 0; j < 4; ++j) {
            const int col = colBase + j * 16 + fr;
            const float bv = BIAS ? bias[col] : 0.f;
#pragma unroll
            for (int r = 0; r < 4; ++r) {
                const int row = rowb + r;
                if (row < M) {
                    float v = acc[i][j][r] + bv;
                    if (RELU) v = fmaxf(v, 0.f);
                    const long o = (long)row * Ncol + col;
                    if (OUTBF) Cb[o] = f2bf(v);
                    else       Cf[o] = v;
                }
            }
        }
    }
}

// == fused heads: [mu|lv] = h2 @ (Wmu|Wlv) pair; z; cap — BM=64 BN=128 K=256 =
__global__ __launch_bounds__(256) void k_gemm_heads(
        const unsigned short* __restrict__ A,
        const unsigned short* __restrict__ Bth, const unsigned short* __restrict__ Btl,
        const float* __restrict__ bmu, const float* __restrict__ blv,
        const float* __restrict__ eps, const float* __restrict__ Wcap,
        const float* __restrict__ bcap, float* __restrict__ mu,
        float* __restrict__ lv, unsigned short* __restrict__ Zh,
        float* __restrict__ cap, int M) {
    constexpr int K = 256;
    __shared__ unsigned short Ash[64][40];
    __shared__ unsigned short Bsh[128][40];
    __shared__ unsigned short Bsl[128][40];
    const int tid = threadIdx.x;
    const int lane = tid & 63, w = tid >> 6;
    const int fr = lane & 15, quad = lane >> 4;
    const int wm0 = w * 16;
    const int rowBase = blockIdx.x * 64;

    const int arow = tid >> 2;                 // 0..63
    const int aseg = (tid & 3) << 3;           // 0,8,16,24
    int agrow = rowBase + arow; if (agrow >= M) agrow = M - 1;
    const long abase = (long)agrow * K + aseg;
    const int brow = tid >> 1;                 // 0..127
    const int bseg = (tid & 1) << 4;           // 0 | 16
    const long bbase = (long)brow * K + bseg;

    f32x4 acc[8];
#pragma unroll
    for (int j = 0; j < 8; ++j) acc[j] = (f32x4){0.f, 0.f, 0.f, 0.f};

    for (int k0 = 0; k0 < K; k0 += 32) {
        *(bf16x8*)&Ash[arow][aseg] = *(const bf16x8*)&A[abase + k0];
        *(bf16x8*)&Bsh[brow][bseg]     = *(const bf16x8*)&Bth[bbase + k0];
        *(bf16x8*)&Bsh[brow][bseg + 8] = *(const bf16x8*)&Bth[bbase + k0 + 8];
        *(bf16x8*)&Bsl[brow][bseg]     = *(const bf16x8*)&Btl[bbase + k0];
        *(bf16x8*)&Bsl[brow][bseg + 8] = *(const bf16x8*)&Btl[bbase + k0 + 8];
        __syncthreads();
        bf16x8 ahf = *(const bf16x8*)&Ash[wm0 + fr][quad * 8];
#pragma unroll
        for (int j = 0; j < 8; ++j) {
            bf16x8 bhf = *(const bf16x8*)&Bsh[j * 16 + fr][quad * 8];
            bf16x8 blf = *(const bf16x8*)&Bsl[j * 16 + fr][quad * 8];
            acc[j] = __builtin_amdgcn_mfma_f32_16x16x32_bf16(ahf, bhf, acc[j], 0, 0, 0);
            acc[j] = __builtin_amdgcn_mfma_f32_16x16x32_bf16(ahf, blf, acc[j], 0, 0, 0);
        }
        __syncthreads();
    }

    float capacc[4] = {0.f, 0.f, 0.f, 0.f};
#pragma unroll
    for (int j = 0; j < 4; ++j) {
        const int c = j * 16 + fr;             // latent index 0..63
        const float bm = bmu[c], bl = blv[c];
        const float wc = Wcap[c];
#pragma unroll
        for (int r = 0; r < 4; ++r) {
            const int row = rowBase + wm0 + quad * 4 + r;
            if (row < M) {
                const long o = (long)row * 64 + c;
                float mv = acc[j][r] + bm;
                float lvv = acc[j + 4][r] + bl;
                mu[o] = mv;
                lv[o] = lvv;
                float zz = fmaf(eps[o], expf(0.5f * lvv), mv);
                Zh[o] = f2bf(zz);
                capacc[r] = fmaf(zz, wc, capacc[r]);
            }
        }
    }
    const float b0 = bcap[0];
#pragma unroll
    for (int r = 0; r < 4; ++r) {
        float v = capacc[r];
        v += __shfl_xor(v, 1, 64);
        v += __shfl_xor(v, 2, 64);
        v += __shfl_xor(v, 4, 64);
        v += __shfl_xor(v, 8, 64);
        if (fr == 0) {
            const int row = rowBase + wm0 + quad * 4 + r;
            if (row < M) cap[row] = 1.f / (1.f + expf(-(v + b0)));
        }
    }
}

// ========= conv1 aggregation from bf16 table -> h1 bf16 ====================
__global__ __launch_bounds__(256) void k_agg_tab(
        const unsigned short* __restrict__ tab, const int* __restrict__ x,
        const int* __restrict__ row_ptr, const int* __restrict__ csr_src,
        const float* __restrict__ dinv, const float* __restrict__ bias,
        unsigned short* __restrict__ h1, int N) {
    const int wave = threadIdx.x >> 6;
    const int lane = threadIdx.x & 63;
    const int node = blockIdx.x * 4 + wave;
    if (node >= N) return;
    const ushort4* t4 = (const ushort4*)tab;   // row = 64 ushort4
    const float di = dinv[node];
    const float selfw = di * di;
    ushort4 a = t4[(long)x[node] * 64 + lane];
    float ax = bf2f(a.x) * selfw, ay = bf2f(a.y) * selfw;
    float az = bf2f(a.z) * selfw, aw = bf2f(a.w) * selfw;
    const int beg = row_ptr[node], end = row_ptr[node + 1];
    for (int e = beg; e < end; ++e) {
        int s = csr_src[e];
        float wgt = dinv[s] * di;
        ushort4 v = t4[(long)x[s] * 64 + lane];
        ax = fmaf(bf2f(v.x), wgt, ax); ay = fmaf(bf2f(v.y), wgt, ay);
        az = fmaf(bf2f(v.z), wgt, az); aw = fmaf(bf2f(v.w), wgt, aw);
    }
    float4 b = ((const float4*)bias)[lane];
    ax = fmaxf(ax + b.x, 0.f); ay = fmaxf(ay + b.y, 0.f);
    az = fmaxf(az + b.z, 0.f); aw = fmaxf(aw + b.w, 0.f);
    ushort4 o;
    o.x = f2bf(ax); o.y = f2bf(ay); o.z = f2bf(az); o.w = f2bf(aw);
    ((ushort4*)h1)[(long)node * 64 + lane] = o;
}

// ========= conv2 aggregation: a2 = A_hat h1 (bf16 gather, bf16 out) ========
__global__ __launch_bounds__(256) void k_agg_nb(
        const unsigned short* __restrict__ h1, const int* __restrict__ row_ptr,
        const int* __restrict__ csr_src, const float* __restrict__ dinv,
        unsigned short* __restrict__ Ob, int N) {
    const int wave = threadIdx.x >> 6;
    const int lane = threadIdx.x & 63;
    const int node = blockIdx.x * 4 + wave;
    if (node >= N) return;
    const ushort4* h4 = (const ushort4*)h1;
    const float di = dinv[node];
    const float selfw = di * di;
    ushort4 a = h4[(long)node * 64 + lane];
    float ax = bf2f(a.x) * selfw, ay = bf2f(a.y) * selfw;
    float az = bf2f(a.z) * selfw, aw = bf2f(a.w) * selfw;
    const int beg = row_ptr[node], end = row_ptr[node + 1];
    int e = beg;
    for (; e + 1 < end; e += 2) {
        int s0 = csr_src[e], s1 = csr_src[e + 1];
        float w0 = dinv[s0] * di, w1 = dinv[s1] * di;
        ushort4 v0 = h4[(long)s0 * 64 + lane];
        ushort4 v1 = h4[(long)s1 * 64 + lane];
        ax = fmaf(bf2f(v0.x), w0, ax); ay = fmaf(bf2f(v0.y), w0, ay);
        az = fmaf(bf2f(v0.z), w0, az); aw = fmaf(bf2f(v0.w), w0, aw);
        ax = fmaf(bf2f(v1.x), w1, ax); ay = fmaf(bf2f(v1.y), w1, ay);
        az = fmaf(bf2f(v1.z), w1, az); aw = fmaf(bf2f(v1.w), w1, aw);
    }
    if (e < end) {
        int s = csr_src[e];
        float wgt = dinv[s] * di;
        ushort4 v = h4[(long)s * 64 + lane];
        ax = fmaf(bf2f(v.x), wgt, ax); ay = fmaf(bf2f(v.y), wgt, ay);
        az = fmaf(bf2f(v.z), wgt, az); aw = fmaf(bf2f(v.w), wgt, aw);
    }
    ushort4 o;
    o.x = f2bf(ax); o.y = f2bf(ay); o.z = f2bf(az); o.w = f2bf(aw);
    ((ushort4*)Ob)[(long)node * 64 + lane] = o;
}

extern "C" void kernel_launch(void* const* d_in, const int* in_sizes, int n_in,
                              void* d_out, int out_size, void* d_ws, size_t ws_size,
                              hipStream_t stream) {
    const int*   x    = (const int*)d_in[0];
    const int*   ei   = (const int*)d_in[1];
    const float* eps  = (const float*)d_in[2];
    const float* emb  = (const float*)d_in[3];
    const float* W1   = (const float*)d_in[4];
    const float* b1   = (const float*)d_in[5];
    const float* W2   = (const float*)d_in[6];
    const float* b2   = (const float*)d_in[7];
    const float* Wmu  = (const float*)d_in[8];
    const float* bmu  = (const float*)d_in[9];
    const float* Wlv  = (const float*)d_in[10];
    const float* blv  = (const float*)d_in[11];
    const float* W3   = (const float*)d_in[12];
    const float* b3   = (const float*)d_in[13];
    const float* W4   = (const float*)d_in[14];
    const float* b4   = (const float*)d_in[15];
    const float* Wcap = (const float*)d_in[16];
    const float* bcap = (const float*)d_in[17];

    const int N = in_sizes[0];
    const int E = in_sizes[1] / 2;
    const int H = in_sizes[5];            // 256
    const int L = in_sizes[9];            // 64
    const int V = in_sizes[15];           // 128
    const int F = in_sizes[4] / H;        // 128

    const int* src = ei;
    const int* dst = ei + E;

    // ---- workspace carve-up ----
    char* w = (char*)d_ws;
    unsigned short* h1b  = (unsigned short*)w; w += (size_t)N * H * 2;  // bf16 h1
    unsigned short* a2b  = (unsigned short*)w; w += (size_t)N * H * 2;  // a2, later t
    unsigned short* h2b  = (unsigned short*)w; w += (size_t)N * H * 2;  // h2
    unsigned short* zh   = (unsigned short*)w; w += (size_t)N * L * 2;  // z
    int*   degint = (int*)w;   w += (size_t)N * 4;
    int*   rowp   = (int*)w;   w += (size_t)(N + 1) * 4;
    int*   cursor = (int*)w;   w += (size_t)N * 4;
    float* dinv   = (float*)w; w += (size_t)N * 4;
    int*   bsum   = (int*)w;   w += 256 * 4;
    int*   csrsrc = (int*)w;   w += (size_t)E * 4;
    float* embW1  = (float*)w; w += (size_t)V * H * 4;
    unsigned short* tabH  = (unsigned short*)w; w += (size_t)V * H * 2;
    unsigned short* W2th  = (unsigned short*)w; w += (size_t)H * H * 2;
    unsigned short* W2tl  = (unsigned short*)w; w += (size_t)H * H * 2;
    unsigned short* Wmlth = (unsigned short*)w; w += (size_t)H * 2 * L * 2; // [128][256]
    unsigned short* Wmltl = (unsigned short*)w; w += (size_t)H * 2 * L * 2;
    unsigned short* W3th  = (unsigned short*)w; w += (size_t)L * H * 2;   // [256][64]
    unsigned short* W3tl  = (unsigned short*)w; w += (size_t)L * H * 2;
    unsigned short* W4th  = (unsigned short*)w; w += (size_t)H * V * 2;   // [128][256]
    unsigned short* W4tl  = (unsigned short*)w; w += (size_t)H * V * 2;

    unsigned short* tb = a2b;   // a2 dead after GEMM2; reuse for t

    float* outp    = (float*)d_out;
    float* recon   = outp;                               // [N, V]
    float* cap     = outp + (size_t)N * V;               // [N, 1]
    float* mu      = outp + (size_t)N * V + N;           // [N, L]
    float* logvar  = mu + (size_t)N * L;                 // [N, L]

    const int nN  = (N + 255) / 256;
    const int nE  = (E + 255) / 256;
    const int nSc = (N + SCAN_BLOCK - 1) / SCAN_BLOCK;
    const int gM128 = (N + 127) / 128;
    const int gM64  = (N + 63) / 64;

    // ---- degree / dinv / CSR ----
    k_init<<<nN, 256, 0, stream>>>(degint, cursor, N);
    k_deg_count<<<nE, 256, 0, stream>>>(dst, degint, E);
    k_dinv<<<nN, 256, 0, stream>>>(degint, dinv, N);
    k_scan_local<<<nSc, SCAN_BLOCK, 0, stream>>>(degint, rowp, bsum, N);
    k_scan_bsum<<<1, 64, 0, stream>>>(bsum, nSc);
    k_scan_add<<<nN, 256, 0, stream>>>(rowp, bsum, N, E);
    k_csr_fill<<<nE, 256, 0, stream>>>(src, dst, rowp, cursor, csrsrc, E);

    // ---- weight conversions (tiny) ----
    k_cvtB<<<(H * H + 255) / 256, 256, 0, stream>>>(W2, W2th, W2tl, H, H);
    k_cvtB<<<(H * L + 255) / 256, 256, 0, stream>>>(Wmu, Wmlth, Wmltl, H, L);
    k_cvtB<<<(H * L + 255) / 256, 256, 0, stream>>>(
        Wlv, Wmlth + (size_t)L * H, Wmltl + (size_t)L * H, H, L);
    k_cvtB<<<(L * H + 255) / 256, 256, 0, stream>>>(W3, W3th, W3tl, L, H);
    k_cvtB<<<(H * V + 255) / 256, 256, 0, stream>>>(W4, W4th, W4tl, H, V);

    // ---- conv1: embW1 = emb @ W1 (fp32) -> bf16 table; agg -> h1 bf16 ----
    k_gemm_f32<<<dim3(V / 64, H / 64), 256, 0, stream>>>(emb, W1, embW1, V, F, H);
    k_cvt_tab<<<(V * H + 255) / 256, 256, 0, stream>>>(embW1, tabH, V * H);
    k_agg_tab<<<(N + 3) / 4, 256, 0, stream>>>(
        tabH, x, rowp, csrsrc, dinv, b1, h1b, N);

    // ---- conv2: a2 = A_hat h1; h2 = relu(a2 @ W2 + b2) -> bf16 ----
    k_agg_nb<<<(N + 3) / 4, 256, 0, stream>>>(h1b, rowp, csrsrc, dinv, a2b, N);
    k_gemm_mfma<true, true, true><<<dim3(gM128, H / 64), 256, 0, stream>>>(
        a2b, W2th, W2tl, b2, nullptr, h2b, N, H, H);

    // ---- fused heads: mu, logvar, z, cap ----
    k_gemm_heads<<<gM64, 256, 0, stream>>>(
        h2b, Wmlth, Wmltl, bmu, blv, eps, Wcap, bcap, mu, logvar, zh, cap, N);

    // ---- decode: t = relu(z@W3+b3) bf16; recon = t@W4+b4 fp32 ----
    k_gemm_mfma<true, true, true><<<dim3(gM128, H / 64), 256, 0, stream>>>(
        zh, W3th, W3tl, b3, nullptr, tb, N, L, H);
    k_gemm_mfma<false, true, false><<<dim3(gM128, V / 64), 256, 0, stream>>>(
        tb, W4th, W4tl, b4, recon, nullptr, N, H, V);
}

// Round 7
// 428.169 us; speedup vs baseline: 2.6198x; 1.0971x over previous
//
#include <hip/hip_runtime.h>
#include <math.h>

// ---------------------------------------------------------------------------
// GCN-VAE forward, round 7.
//  - Edge packs {w=dinv[s]*dinv[d], tok/srcrow} built at CSR-fill; self-loops
//    are regular CSR entries. Agg kernels: pack -> gather (chain depth 2),
//    4-edge unroll for MLP. (R6 showed agg_tab latency-bound: 5% HBM, 33% VALU)
//  - dinv folded into scan_local; bf16 table written by GEMM epilogue;
//    5 weight-cvt launches merged into one.
// ---------------------------------------------------------------------------

typedef __attribute__((ext_vector_type(8))) short bf16x8;
typedef __attribute__((ext_vector_type(4))) float f32x4;

__device__ inline unsigned short f2bf(float x) {
    unsigned u = __float_as_uint(x);
    return (unsigned short)((u + 0x7FFFu + ((u >> 16) & 1u)) >> 16);
}
__device__ inline float bf2f(unsigned short h) {
    return __uint_as_float(((unsigned)h) << 16);
}

// ============================ CSR build ====================================
__global__ __launch_bounds__(256) void k_init(int* __restrict__ degint,
                                              int* __restrict__ cursor, int N) {
    int i = blockIdx.x * 256 + threadIdx.x;
    if (i < N) { degint[i] = 1; cursor[i] = 0; }   // 1 = self-loop
}

__global__ __launch_bounds__(256) void k_deg_count(const int* __restrict__ dst,
                                                   int* __restrict__ degint, int E) {
    int e = blockIdx.x * 256 + threadIdx.x;
    if (e < E) atomicAdd(&degint[dst[e]], 1);
}

// scan over degint (self-inclusive); also emits dinv = rsqrt(deg)
#define SCAN_BLOCK 1024
__global__ __launch_bounds__(SCAN_BLOCK) void k_scan_local(
        const int* __restrict__ degint, int* __restrict__ row_ptr,
        int* __restrict__ bsum, float* __restrict__ dinv, int N) {
    __shared__ int s[SCAN_BLOCK];
    int gid = blockIdx.x * SCAN_BLOCK + threadIdx.x;
    int d = (gid < N) ? degint[gid] : 0;
    if (gid < N) dinv[gid] = rsqrtf((float)d);
    s[threadIdx.x] = d;
    __syncthreads();
    for (int off = 1; off < SCAN_BLOCK; off <<= 1) {
        int t = (threadIdx.x >= off) ? s[threadIdx.x - off] : 0;
        __syncthreads();
        s[threadIdx.x] += t;
        __syncthreads();
    }
    if (gid < N) row_ptr[gid] = s[threadIdx.x] - d;          // exclusive
    if (threadIdx.x == SCAN_BLOCK - 1) bsum[blockIdx.x] = s[SCAN_BLOCK - 1];
}

__global__ void k_scan_bsum(int* __restrict__ bsum, int nb) {
    if (blockIdx.x == 0 && threadIdx.x == 0) {
        int acc = 0;
        for (int i = 0; i < nb; ++i) { int v = bsum[i]; bsum[i] = acc; acc += v; }
    }
}

__global__ __launch_bounds__(256) void k_scan_add(int* __restrict__ row_ptr,
                                                  const int* __restrict__ bsum,
                                                  int N, int T) {
    int gid = blockIdx.x * 256 + threadIdx.x;
    if (gid < N) row_ptr[gid] += bsum[gid / SCAN_BLOCK];
    if (gid == 0) row_ptr[N] = T;                 // T = E + N
}

// fill edge packs: packA = {w, x[src]}, packB = {w, src}, w=dinv[s]*dinv[d]
__global__ __launch_bounds__(256) void k_csr_fill(
        const int* __restrict__ src, const int* __restrict__ dst,
        const int* __restrict__ x, const float* __restrict__ dinv,
        const int* __restrict__ row_ptr, int* __restrict__ cursor,
        int2* __restrict__ packA, int2* __restrict__ packB, int E) {
    int e = blockIdx.x * 256 + threadIdx.x;
    if (e < E) {
        int s = src[e], d = dst[e];
        float w = dinv[s] * dinv[d];
        int pos = row_ptr[d] + atomicAdd(&cursor[d], 1);
        packA[pos] = make_int2(__float_as_int(w), x[s]);
        packB[pos] = make_int2(__float_as_int(w), s);
    }
}

// self-loop entries: w = dinv[i]^2
__global__ __launch_bounds__(256) void k_self_fill(
        const int* __restrict__ x, const float* __restrict__ dinv,
        const int* __restrict__ row_ptr, int* __restrict__ cursor,
        int2* __restrict__ packA, int2* __restrict__ packB, int N) {
    int i = blockIdx.x * 256 + threadIdx.x;
    if (i < N) {
        float di = dinv[i];
        float w = di * di;
        int pos = row_ptr[i] + atomicAdd(&cursor[i], 1);
        packA[pos] = make_int2(__float_as_int(w), x[i]);
        packB[pos] = make_int2(__float_as_int(w), i);
    }
}

// ===== merged weight transpose+split: 5 jobs, B[K,N] -> Bt{h,l}[N,K] =======
__global__ __launch_bounds__(256) void k_cvt_all(
        const float* __restrict__ B0, unsigned short* __restrict__ h0,
        unsigned short* __restrict__ l0, int K0, int N0,
        const float* __restrict__ B1, unsigned short* __restrict__ h1,
        unsigned short* __restrict__ l1, int K1, int N1,
        const float* __restrict__ B2, unsigned short* __restrict__ h2,
        unsigned short* __restrict__ l2, int K2, int N2,
        const float* __restrict__ B3, unsigned short* __restrict__ h3,
        unsigned short* __restrict__ l3, int K3, int N3,
        const float* __restrict__ B4, unsigned short* __restrict__ h4,
        unsigned short* __restrict__ l4, int K4, int N4) {
    const float* B; unsigned short *Bh, *Bl; int K, Ncol;
    switch (blockIdx.y) {
        case 0: B = B0; Bh = h0; Bl = l0; K = K0; Ncol = N0; break;
        case 1: B = B1; Bh = h1; Bl = l1; K = K1; Ncol = N1; break;
        case 2: B = B2; Bh = h2; Bl = l2; K = K2; Ncol = N2; break;
        case 3: B = B3; Bh = h3; Bl = l3; K = K3; Ncol = N3; break;
        default: B = B4; Bh = h4; Bl = l4; K = K4; Ncol = N4; break;
    }
    int i = blockIdx.x * 256 + threadIdx.x;
    if (i >= K * Ncol) return;
    int k = i / Ncol, n = i - k * Ncol;
    float v = B[i];
    unsigned short h = f2bf(v);
    Bh[(long)n * K + k] = h;
    Bl[(long)n * K + k] = f2bf(v - bf2f(h));
}

// ============ small fp32 GEMM with optional bf16 output (embW1) ============
template<bool OUTBF>
__global__ __launch_bounds__(256) void k_gemm_f32(
        const float* __restrict__ A, const float* __restrict__ B,
        float* __restrict__ C, unsigned short* __restrict__ Cb,
        int M, int K, int Ncol) {
    constexpr int BM = 64, BN = 64, BK = 16;
    __shared__ float As[BK][BM];
    __shared__ float Bs[BK][BN];
    const int tid = threadIdx.x;
    const int tx = tid & 15, ty = tid >> 4;
    const int rowBase = blockIdx.x * BM;
    const int colBase = blockIdx.y * BN;
    const int lr = tid >> 2, lc4 = tid & 3;
    const int br = tid >> 4, bc4 = tid & 15;
    const int arow = rowBase + lr;
    const int K4 = K >> 2, N4 = Ncol >> 2;
    const float4* A4 = (const float4*)A;
    const float4* B4 = (const float4*)B;
    float acc[4][4] = {{0.f}};
    for (int k0 = 0; k0 < K; k0 += BK) {
        float4 av = make_float4(0.f, 0.f, 0.f, 0.f);
        if (arow < M) av = A4[(long)arow * K4 + (k0 >> 2) + lc4];
        As[lc4 * 4 + 0][lr] = av.x;
        As[lc4 * 4 + 1][lr] = av.y;
        As[lc4 * 4 + 2][lr] = av.z;
        As[lc4 * 4 + 3][lr] = av.w;
        float4 bv = B4[(long)(k0 + br) * N4 + (colBase >> 2) + bc4];
        *(float4*)&Bs[br][bc4 * 4] = bv;
        __syncthreads();
#pragma unroll
        for (int k = 0; k < BK; ++k) {
            float4 a4v = *(const float4*)&As[k][ty * 4];
            float4 b4v = *(const float4*)&Bs[k][tx * 4];
            float aa[4] = {a4v.x, a4v.y, a4v.z, a4v.w};
            float bb[4] = {b4v.x, b4v.y, b4v.z, b4v.w};
#pragma unroll
            for (int i = 0; i < 4; ++i)
#pragma unroll
                for (int j = 0; j < 4; ++j)
                    acc[i][j] = fmaf(aa[i], bb[j], acc[i][j]);
        }
        __syncthreads();
    }
#pragma unroll
    for (int i = 0; i < 4; ++i) {
        int row = rowBase + ty * 4 + i;
        if (row < M) {
            if (OUTBF) {
                ushort4 o;
                o.x = f2bf(acc[i][0]); o.y = f2bf(acc[i][1]);
                o.z = f2bf(acc[i][2]); o.w = f2bf(acc[i][3]);
                *(ushort4*)&Cb[(long)row * Ncol + colBase + tx * 4] = o;
            } else {
                float4 o = make_float4(acc[i][0], acc[i][1], acc[i][2], acc[i][3]);
                ((float4*)C)[(long)row * N4 + (colBase >> 2) + tx] = o;
            }
        }
    }
}

// ====== MFMA GEMM, 2-term split: C = A(bf16) @ (Bh+Bl), BM=128 BN=64 BK=32 =
template<bool RELU, bool BIAS, bool OUTBF>
__global__ __launch_bounds__(256) void k_gemm_mfma(
        const unsigned short* __restrict__ A,
        const unsigned short* __restrict__ Bth, const unsigned short* __restrict__ Btl,
        const float* __restrict__ bias, float* __restrict__ Cf,
        unsigned short* __restrict__ Cb, int M, int K, int Ncol) {
    __shared__ unsigned short Ash[128][40];
    __shared__ unsigned short Bsh[64][40];
    __shared__ unsigned short Bsl[64][40];
    const int tid = threadIdx.x;
    const int lane = tid & 63, w = tid >> 6;
    const int fr = lane & 15, quad = lane >> 4;
    const int wm0 = w * 32;
    const int rowBase = blockIdx.x * 128;
    const int colBase = blockIdx.y * 64;

    const int arow = tid >> 1;
    const int ahalf = (tid & 1) << 4;
    int agrow = rowBase + arow; if (agrow >= M) agrow = M - 1;
    const long abase = (long)agrow * K + ahalf;
    const int bt = tid & 127;
    const int brow = bt >> 1;
    const int bhalf = (bt & 1) << 4;
    const long bbase = (long)(colBase + brow) * K + bhalf;
    const unsigned short* Bsrc = (tid < 128) ? Bth : Btl;
    unsigned short* Bdst = (tid < 128) ? &Bsh[brow][bhalf] : &Bsl[brow][bhalf];

    f32x4 acc[2][4];
#pragma unroll
    for (int i = 0; i < 2; ++i)
#pragma unroll
        for (int j = 0; j < 4; ++j) acc[i][j] = (f32x4){0.f, 0.f, 0.f, 0.f};

    for (int k0 = 0; k0 < K; k0 += 32) {
        *(bf16x8*)&Ash[arow][ahalf]     = *(const bf16x8*)&A[abase + k0];
        *(bf16x8*)&Ash[arow][ahalf + 8] = *(const bf16x8*)&A[abase + k0 + 8];
        *(bf16x8*)Bdst       = *(const bf16x8*)&Bsrc[bbase + k0];
        *(bf16x8*)(Bdst + 8) = *(const bf16x8*)&Bsrc[bbase + k0 + 8];
        __syncthreads();
        bf16x8 ahf[2], bhf[4], blf[4];
#pragma unroll
        for (int i = 0; i < 2; ++i)
            ahf[i] = *(const bf16x8*)&Ash[wm0 + i * 16 + fr][quad * 8];
#pragma unroll
        for (int j = 0; j < 4; ++j) {
            bhf[j] = *(const bf16x8*)&Bsh[j * 16 + fr][quad * 8];
            blf[j] = *(const bf16x8*)&Bsl[j * 16 + fr][quad * 8];
        }
#pragma unroll
        for (int i = 0; i < 2; ++i)
#pragma unroll
            for (int j = 0; j < 4; ++j) {
                acc[i][j] = __builtin_amdgcn_mfma_f32_16x16x32_bf16(
                    ahf[i], bhf[j], acc[i][j], 0, 0, 0);
                acc[i][j] = __builtin_amdgcn_mfma_f32_16x16x32_bf16(
                    ahf[i], blf[j], acc[i][j], 0, 0, 0);
            }
        __syncthreads();
    }

#pragma unroll
    for (int i = 0; i < 2; ++i) {
        const int rowb = rowBase + wm0 + i * 16 + quad * 4;
#pragma unroll
        for (int j = 0; j < 4; ++j) {
            const int col = colBase + j * 16 + fr;
            const float bv = BIAS ? bias[col] : 0.f;
#pragma unroll
            for (int r = 0; r < 4; ++r) {
                const int row = rowb + r;
                if (row < M) {
                    float v = acc[i][j][r] + bv;
                    if (RELU) v = fmaxf(v, 0.f);
                    const long o = (long)row * Ncol + col;
                    if (OUTBF) Cb[o] = f2bf(v);
                    else       Cf[o] = v;
                }
            }
        }
    }
}

// == fused heads: [mu|lv] = h2 @ (Wmu|Wlv) pair; z; cap — BM=64 BN=128 K=256 =
__global__ __launch_bounds__(256) void k_gemm_heads(
        const unsigned short* __restrict__ A,
        const unsigned short* __restrict__ Bth, const unsigned short* __restrict__ Btl,
        const float* __restrict__ bmu, const float* __restrict__ blv,
        const float* __restrict__ eps, const float* __restrict__ Wcap,
        const float* __restrict__ bcap, float* __restrict__ mu,
        float* __restrict__ lv, unsigned short* __restrict__ Zh,
        float* __restrict__ cap, int M) {
    constexpr int K = 256;
    __shared__ unsigned short Ash[64][40];
    __shared__ unsigned short Bsh[128][40];
    __shared__ unsigned short Bsl[128][40];
    const int tid = threadIdx.x;
    const int lane = tid & 63, w = tid >> 6;
    const int fr = lane & 15, quad = lane >> 4;
    const int wm0 = w * 16;
    const int rowBase = blockIdx.x * 64;

    const int arow = tid >> 2;
    const int aseg = (tid & 3) << 3;
    int agrow = rowBase + arow; if (agrow >= M) agrow = M - 1;
    const long abase = (long)agrow * K + aseg;
    const int brow = tid >> 1;
    const int bseg = (tid & 1) << 4;
    const long bbase = (long)brow * K + bseg;

    f32x4 acc[8];
#pragma unroll
    for (int j = 0; j < 8; ++j) acc[j] = (f32x4){0.f, 0.f, 0.f, 0.f};

    for (int k0 = 0; k0 < K; k0 += 32) {
        *(bf16x8*)&Ash[arow][aseg] = *(const bf16x8*)&A[abase + k0];
        *(bf16x8*)&Bsh[brow][bseg]     = *(const bf16x8*)&Bth[bbase + k0];
        *(bf16x8*)&Bsh[brow][bseg + 8] = *(const bf16x8*)&Bth[bbase + k0 + 8];
        *(bf16x8*)&Bsl[brow][bseg]     = *(const bf16x8*)&Btl[bbase + k0];
        *(bf16x8*)&Bsl[brow][bseg + 8] = *(const bf16x8*)&Btl[bbase + k0 + 8];
        __syncthreads();
        bf16x8 ahf = *(const bf16x8*)&Ash[wm0 + fr][quad * 8];
#pragma unroll
        for (int j = 0; j < 8; ++j) {
            bf16x8 bhf = *(const bf16x8*)&Bsh[j * 16 + fr][quad * 8];
            bf16x8 blf = *(const bf16x8*)&Bsl[j * 16 + fr][quad * 8];
            acc[j] = __builtin_amdgcn_mfma_f32_16x16x32_bf16(ahf, bhf, acc[j], 0, 0, 0);
            acc[j] = __builtin_amdgcn_mfma_f32_16x16x32_bf16(ahf, blf, acc[j], 0, 0, 0);
        }
        __syncthreads();
    }

    float capacc[4] = {0.f, 0.f, 0.f, 0.f};
#pragma unroll
    for (int j = 0; j < 4; ++j) {
        const int c = j * 16 + fr;
        const float bm = bmu[c], bl = blv[c];
        const float wc = Wcap[c];
#pragma unroll
        for (int r = 0; r < 4; ++r) {
            const int row = rowBase + wm0 + quad * 4 + r;
            if (row < M) {
                const long o = (long)row * 64 + c;
                float mv = acc[j][r] + bm;
                float lvv = acc[j + 4][r] + bl;
                mu[o] = mv;
                lv[o] = lvv;
                float zz = fmaf(eps[o], expf(0.5f * lvv), mv);
                Zh[o] = f2bf(zz);
                capacc[r] = fmaf(zz, wc, capacc[r]);
            }
        }
    }
    const float b0 = bcap[0];
#pragma unroll
    for (int r = 0; r < 4; ++r) {
        float v = capacc[r];
        v += __shfl_xor(v, 1, 64);
        v += __shfl_xor(v, 2, 64);
        v += __shfl_xor(v, 4, 64);
        v += __shfl_xor(v, 8, 64);
        if (fr == 0) {
            const int row = rowBase + wm0 + quad * 4 + r;
            if (row < M) cap[row] = 1.f / (1.f + expf(-(v + b0)));
        }
    }
}

// ==== conv1 agg: h1 = relu(b1 + sum_e w_e * T[tok_e]); pack -> gather ======
__global__ __launch_bounds__(256) void k_agg_tab(
        const unsigned short* __restrict__ tab, const int* __restrict__ row_ptr,
        const int2* __restrict__ packA, const float* __restrict__ bias,
        unsigned short* __restrict__ h1, int N) {
    const int wave = threadIdx.x >> 6;
    const int lane = threadIdx.x & 63;
    const int node = blockIdx.x * 4 + wave;
    if (node >= N) return;
    const ushort4* t4 = (const ushort4*)tab;
    float ax = 0.f, ay = 0.f, az = 0.f, aw = 0.f;
    const int beg = row_ptr[node], end = row_ptr[node + 1];
    int e = beg;
    for (; e + 4 <= end; e += 4) {
        int2 p0 = packA[e], p1 = packA[e + 1], p2 = packA[e + 2], p3 = packA[e + 3];
        ushort4 v0 = t4[(long)p0.y * 64 + lane];
        ushort4 v1 = t4[(long)p1.y * 64 + lane];
        ushort4 v2 = t4[(long)p2.y * 64 + lane];
        ushort4 v3 = t4[(long)p3.y * 64 + lane];
        float w0 = __int_as_float(p0.x), w1 = __int_as_float(p1.x);
        float w2 = __int_as_float(p2.x), w3 = __int_as_float(p3.x);
        ax = fmaf(bf2f(v0.x), w0, ax); ay = fmaf(bf2f(v0.y), w0, ay);
        az = fmaf(bf2f(v0.z), w0, az); aw = fmaf(bf2f(v0.w), w0, aw);
        ax = fmaf(bf2f(v1.x), w1, ax); ay = fmaf(bf2f(v1.y), w1, ay);
        az = fmaf(bf2f(v1.z), w1, az); aw = fmaf(bf2f(v1.w), w1, aw);
        ax = fmaf(bf2f(v2.x), w2, ax); ay = fmaf(bf2f(v2.y), w2, ay);
        az = fmaf(bf2f(v2.z), w2, az); aw = fmaf(bf2f(v2.w), w2, aw);
        ax = fmaf(bf2f(v3.x), w3, ax); ay = fmaf(bf2f(v3.y), w3, ay);
        az = fmaf(bf2f(v3.z), w3, az); aw = fmaf(bf2f(v3.w), w3, aw);
    }
    for (; e < end; ++e) {
        int2 p = packA[e];
        float w0 = __int_as_float(p.x);
        ushort4 v = t4[(long)p.y * 64 + lane];
        ax = fmaf(bf2f(v.x), w0, ax); ay = fmaf(bf2f(v.y), w0, ay);
        az = fmaf(bf2f(v.z), w0, az); aw = fmaf(bf2f(v.w), w0, aw);
    }
    float4 b = ((const float4*)bias)[lane];
    ax = fmaxf(ax + b.x, 0.f); ay = fmaxf(ay + b.y, 0.f);
    az = fmaxf(az + b.z, 0.f); aw = fmaxf(aw + b.w, 0.f);
    ushort4 o;
    o.x = f2bf(ax); o.y = f2bf(ay); o.z = f2bf(az); o.w = f2bf(aw);
    ((ushort4*)h1)[(long)node * 64 + lane] = o;
}

// ==== conv2 agg: a2 = sum_e w_e * h1[src_e]; pack -> gather ================
__global__ __launch_bounds__(256) void k_agg_nb(
        const unsigned short* __restrict__ h1, const int* __restrict__ row_ptr,
        const int2* __restrict__ packB, unsigned short* __restrict__ Ob, int N) {
    const int wave = threadIdx.x >> 6;
    const int lane = threadIdx.x & 63;
    const int node = blockIdx.x * 4 + wave;
    if (node >= N) return;
    const ushort4* h4 = (const ushort4*)h1;
    float ax = 0.f, ay = 0.f, az = 0.f, aw = 0.f;
    const int beg = row_ptr[node], end = row_ptr[node + 1];
    int e = beg;
    for (; e + 4 <= end; e += 4) {
        int2 p0 = packB[e], p1 = packB[e + 1], p2 = packB[e + 2], p3 = packB[e + 3];
        ushort4 v0 = h4[(long)p0.y * 64 + lane];
        ushort4 v1 = h4[(long)p1.y * 64 + lane];
        ushort4 v2 = h4[(long)p2.y * 64 + lane];
        ushort4 v3 = h4[(long)p3.y * 64 + lane];
        float w0 = __int_as_float(p0.x), w1 = __int_as_float(p1.x);
        float w2 = __int_as_float(p2.x), w3 = __int_as_float(p3.x);
        ax = fmaf(bf2f(v0.x), w0, ax); ay = fmaf(bf2f(v0.y), w0, ay);
        az = fmaf(bf2f(v0.z), w0, az); aw = fmaf(bf2f(v0.w), w0, aw);
        ax = fmaf(bf2f(v1.x), w1, ax); ay = fmaf(bf2f(v1.y), w1, ay);
        az = fmaf(bf2f(v1.z), w1, az); aw = fmaf(bf2f(v1.w), w1, aw);
        ax = fmaf(bf2f(v2.x), w2, ax); ay = fmaf(bf2f(v2.y), w2, ay);
        az = fmaf(bf2f(v2.z), w2, az); aw = fmaf(bf2f(v2.w), w2, aw);
        ax = fmaf(bf2f(v3.x), w3, ax); ay = fmaf(bf2f(v3.y), w3, ay);
        az = fmaf(bf2f(v3.z), w3, az); aw = fmaf(bf2f(v3.w), w3, aw);
    }
    for (; e < end; ++e) {
        int2 p = packB[e];
        float w0 = __int_as_float(p.x);
        ushort4 v = h4[(long)p.y * 64 + lane];
        ax = fmaf(bf2f(v.x), w0, ax); ay = fmaf(bf2f(v.y), w0, ay);
        az = fmaf(bf2f(v.z), w0, az); aw = fmaf(bf2f(v.w), w0, aw);
    }
    ushort4 o;
    o.x = f2bf(ax); o.y = f2bf(ay); o.z = f2bf(az); o.w = f2bf(aw);
    ((ushort4*)Ob)[(long)node * 64 + lane] = o;
}

extern "C" void kernel_launch(void* const* d_in, const int* in_sizes, int n_in,
                              void* d_out, int out_size, void* d_ws, size_t ws_size,
                              hipStream_t stream) {
    const int*   x    = (const int*)d_in[0];
    const int*   ei   = (const int*)d_in[1];
    const float* eps  = (const float*)d_in[2];
    const float* emb  = (const float*)d_in[3];
    const float* W1   = (const float*)d_in[4];
    const float* b1   = (const float*)d_in[5];
    const float* W2   = (const float*)d_in[6];
    const float* b2   = (const float*)d_in[7];
    const float* Wmu  = (const float*)d_in[8];
    const float* bmu  = (const float*)d_in[9];
    const float* Wlv  = (const float*)d_in[10];
    const float* blv  = (const float*)d_in[11];
    const float* W3   = (const float*)d_in[12];
    const float* b3   = (const float*)d_in[13];
    const float* W4   = (const float*)d_in[14];
    const float* b4   = (const float*)d_in[15];
    const float* Wcap = (const float*)d_in[16];
    const float* bcap = (const float*)d_in[17];

    const int N = in_sizes[0];
    const int E = in_sizes[1] / 2;
    const int H = in_sizes[5];            // 256
    const int L = in_sizes[9];            // 64
    const int V = in_sizes[15];           // 128
    const int F = in_sizes[4] / H;        // 128
    const int T = E + N;                  // CSR entries incl. self-loops

    const int* src = ei;
    const int* dst = ei + E;

    // ---- workspace carve-up ----
    char* w = (char*)d_ws;
    unsigned short* h1b  = (unsigned short*)w; w += (size_t)N * H * 2;  // bf16 h1
    unsigned short* a2b  = (unsigned short*)w; w += (size_t)N * H * 2;  // a2, later t
    unsigned short* h2b  = (unsigned short*)w; w += (size_t)N * H * 2;  // h2
    unsigned short* zh   = (unsigned short*)w; w += (size_t)N * L * 2;  // z
    int*   degint = (int*)w;   w += (size_t)N * 4;
    int*   rowp   = (int*)w;   w += (size_t)(N + 1) * 4;
    int*   cursor = (int*)w;   w += (size_t)N * 4;
    float* dinv   = (float*)w; w += (size_t)N * 4;
    int*   bsum   = (int*)w;   w += 256 * 4;
    int2*  packA  = (int2*)w;  w += (size_t)T * 8;
    int2*  packB  = (int2*)w;  w += (size_t)T * 8;
    unsigned short* tabH  = (unsigned short*)w; w += (size_t)V * H * 2;
    unsigned short* W2th  = (unsigned short*)w; w += (size_t)H * H * 2;
    unsigned short* W2tl  = (unsigned short*)w; w += (size_t)H * H * 2;
    unsigned short* Wmlth = (unsigned short*)w; w += (size_t)H * 2 * L * 2;
    unsigned short* Wmltl = (unsigned short*)w; w += (size_t)H * 2 * L * 2;
    unsigned short* W3th  = (unsigned short*)w; w += (size_t)L * H * 2;
    unsigned short* W3tl  = (unsigned short*)w; w += (size_t)L * H * 2;
    unsigned short* W4th  = (unsigned short*)w; w += (size_t)H * V * 2;
    unsigned short* W4tl  = (unsigned short*)w; w += (size_t)H * V * 2;

    unsigned short* tb = a2b;   // a2 dead after GEMM2; reuse for t

    float* outp    = (float*)d_out;
    float* recon   = outp;                               // [N, V]
    float* cap     = outp + (size_t)N * V;               // [N, 1]
    float* mu      = outp + (size_t)N * V + N;           // [N, L]
    float* logvar  = mu + (size_t)N * L;                 // [N, L]

    const int nN  = (N + 255) / 256;
    const int nE  = (E + 255) / 256;
    const int nSc = (N + SCAN_BLOCK - 1) / SCAN_BLOCK;
    const int gM128 = (N + 127) / 128;
    const int gM64  = (N + 63) / 64;

    // ---- degree / dinv / CSR packs ----
    k_init<<<nN, 256, 0, stream>>>(degint, cursor, N);
    k_deg_count<<<nE, 256, 0, stream>>>(dst, degint, E);
    k_scan_local<<<nSc, SCAN_BLOCK, 0, stream>>>(degint, rowp, bsum, dinv, N);
    k_scan_bsum<<<1, 64, 0, stream>>>(bsum, nSc);
    k_scan_add<<<nN, 256, 0, stream>>>(rowp, bsum, N, T);
    k_csr_fill<<<nE, 256, 0, stream>>>(src, dst, x, dinv, rowp, cursor,
                                       packA, packB, E);
    k_self_fill<<<nN, 256, 0, stream>>>(x, dinv, rowp, cursor, packA, packB, N);

    // ---- weight conversions: one launch, 5 jobs ----
    k_cvt_all<<<dim3((H * H + 255) / 256, 5), 256, 0, stream>>>(
        W2, W2th, W2tl, H, H,
        Wmu, Wmlth, Wmltl, H, L,
        Wlv, Wmlth + (size_t)L * H, Wmltl + (size_t)L * H, H, L,
        W3, W3th, W3tl, L, H,
        W4, W4th, W4tl, H, V);

    // ---- conv1: embW1 = emb @ W1 -> bf16 table; agg -> h1 bf16 ----
    k_gemm_f32<true><<<dim3(V / 64, H / 64), 256, 0, stream>>>(
        emb, W1, nullptr, tabH, V, F, H);
    k_agg_tab<<<(N + 3) / 4, 256, 0, stream>>>(tabH, rowp, packA, b1, h1b, N);

    // ---- conv2: a2 = A_hat h1; h2 = relu(a2 @ W2 + b2) -> bf16 ----
    k_agg_nb<<<(N + 3) / 4, 256, 0, stream>>>(h1b, rowp, packB, a2b, N);
    k_gemm_mfma<true, true, true><<<dim3(gM128, H / 64), 256, 0, stream>>>(
        a2b, W2th, W2tl, b2, nullptr, h2b, N, H, H);

    // ---- fused heads: mu, logvar, z, cap ----
    k_gemm_heads<<<gM64, 256, 0, stream>>>(
        h2b, Wmlth, Wmltl, bmu, blv, eps, Wcap, bcap, mu, logvar, zh, cap, N);

    // ---- decode: t = relu(z@W3+b3) bf16; recon = t@W4+b4 fp32 ----
    k_gemm_mfma<true, true, true><<<dim3(gM128, H / 64), 256, 0, stream>>>(
        zh, W3th, W3tl, b3, nullptr, tb, N, L, H);
    k_gemm_mfma<false, true, false><<<dim3(gM128, V / 64), 256, 0, stream>>>(
        tb, W4th, W4tl, b4, recon, nullptr, N, H, V);
}

// Round 8
// 427.839 us; speedup vs baseline: 2.6218x; 1.0008x over previous
//
#include <hip/hip_runtime.h>
#include <math.h>

// ---------------------------------------------------------------------------
// GCN-VAE forward, round 8.
//  - single-bf16 weights (hi/lo split dropped): absmax has been pinned at the
//    output bf16 floor (0.015625) since R1 — split precision was invisible.
//    Halves MFMA work + B staging in all 4 MFMA GEMMs.
//  - k_init replaced by hipMemsetAsync (deg=count+1 folded into scan);
//    csr_fill+self_fill merged; 14 dispatches total.
// ---------------------------------------------------------------------------

typedef __attribute__((ext_vector_type(8))) short bf16x8;
typedef __attribute__((ext_vector_type(4))) float f32x4;

__device__ inline unsigned short f2bf(float x) {
    unsigned u = __float_as_uint(x);
    return (unsigned short)((u + 0x7FFFu + ((u >> 16) & 1u)) >> 16);
}
__device__ inline float bf2f(unsigned short h) {
    return __uint_as_float(((unsigned)h) << 16);
}

// ============================ CSR build ====================================
__global__ __launch_bounds__(256) void k_deg_count(const int* __restrict__ dst,
                                                   int* __restrict__ degint, int E) {
    int e = blockIdx.x * 256 + threadIdx.x;
    if (e < E) atomicAdd(&degint[dst[e]], 1);
}

// scan over (degint+1) (self-inclusive); emits dinv = rsqrt(deg)
#define SCAN_BLOCK 1024
__global__ __launch_bounds__(SCAN_BLOCK) void k_scan_local(
        const int* __restrict__ degint, int* __restrict__ row_ptr,
        int* __restrict__ bsum, float* __restrict__ dinv, int N) {
    __shared__ int s[SCAN_BLOCK];
    int gid = blockIdx.x * SCAN_BLOCK + threadIdx.x;
    int d = (gid < N) ? (degint[gid] + 1) : 0;     // +1 self-loop
    if (gid < N) dinv[gid] = rsqrtf((float)d);
    s[threadIdx.x] = d;
    __syncthreads();
    for (int off = 1; off < SCAN_BLOCK; off <<= 1) {
        int t = (threadIdx.x >= off) ? s[threadIdx.x - off] : 0;
        __syncthreads();
        s[threadIdx.x] += t;
        __syncthreads();
    }
    if (gid < N) row_ptr[gid] = s[threadIdx.x] - d;          // exclusive
    if (threadIdx.x == SCAN_BLOCK - 1) bsum[blockIdx.x] = s[SCAN_BLOCK - 1];
}

__global__ void k_scan_bsum(int* __restrict__ bsum, int nb) {
    if (blockIdx.x == 0 && threadIdx.x == 0) {
        int acc = 0;
        for (int i = 0; i < nb; ++i) { int v = bsum[i]; bsum[i] = acc; acc += v; }
    }
}

__global__ __launch_bounds__(256) void k_scan_add(int* __restrict__ row_ptr,
                                                  const int* __restrict__ bsum,
                                                  int N, int T) {
    int gid = blockIdx.x * 256 + threadIdx.x;
    if (gid < N) row_ptr[gid] += bsum[gid / SCAN_BLOCK];
    if (gid == 0) row_ptr[N] = T;                 // T = E + N
}

// fill edge + self packs: packA = {w, x[src]}, packB = {w, src}
__global__ __launch_bounds__(256) void k_fill(
        const int* __restrict__ src, const int* __restrict__ dst,
        const int* __restrict__ x, const float* __restrict__ dinv,
        const int* __restrict__ row_ptr, int* __restrict__ cursor,
        int2* __restrict__ packA, int2* __restrict__ packB, int E, int N) {
    int e = blockIdx.x * 256 + threadIdx.x;
    if (e < E) {
        int s = src[e], d = dst[e];
        float w = dinv[s] * dinv[d];
        int pos = row_ptr[d] + atomicAdd(&cursor[d], 1);
        packA[pos] = make_int2(__float_as_int(w), x[s]);
        packB[pos] = make_int2(__float_as_int(w), s);
    } else if (e < E + N) {
        int i = e - E;
        float di = dinv[i];
        float w = di * di;
        int pos = row_ptr[i] + atomicAdd(&cursor[i], 1);
        packA[pos] = make_int2(__float_as_int(w), x[i]);
        packB[pos] = make_int2(__float_as_int(w), i);
    }
}

// ===== merged weight transpose: 5 jobs, B[K,N] -> Bt[N,K] bf16 =============
__global__ __launch_bounds__(256) void k_cvt_all(
        const float* __restrict__ B0, unsigned short* __restrict__ h0, int K0, int N0,
        const float* __restrict__ B1, unsigned short* __restrict__ h1, int K1, int N1,
        const float* __restrict__ B2, unsigned short* __restrict__ h2, int K2, int N2,
        const float* __restrict__ B3, unsigned short* __restrict__ h3, int K3, int N3,
        const float* __restrict__ B4, unsigned short* __restrict__ h4, int K4, int N4) {
    const float* B; unsigned short* Bh; int K, Ncol;
    switch (blockIdx.y) {
        case 0: B = B0; Bh = h0; K = K0; Ncol = N0; break;
        case 1: B = B1; Bh = h1; K = K1; Ncol = N1; break;
        case 2: B = B2; Bh = h2; K = K2; Ncol = N2; break;
        case 3: B = B3; Bh = h3; K = K3; Ncol = N3; break;
        default: B = B4; Bh = h4; K = K4; Ncol = N4; break;
    }
    int i = blockIdx.x * 256 + threadIdx.x;
    if (i >= K * Ncol) return;
    int k = i / Ncol, n = i - k * Ncol;
    Bh[(long)n * K + k] = f2bf(B[i]);
}

// ============ small fp32 GEMM with bf16 output (embW1 table) ===============
__global__ __launch_bounds__(256) void k_gemm_f32(
        const float* __restrict__ A, const float* __restrict__ B,
        unsigned short* __restrict__ Cb, int M, int K, int Ncol) {
    constexpr int BM = 64, BN = 64, BK = 16;
    __shared__ float As[BK][BM];
    __shared__ float Bs[BK][BN];
    const int tid = threadIdx.x;
    const int tx = tid & 15, ty = tid >> 4;
    const int rowBase = blockIdx.x * BM;
    const int colBase = blockIdx.y * BN;
    const int lr = tid >> 2, lc4 = tid & 3;
    const int br = tid >> 4, bc4 = tid & 15;
    const int arow = rowBase + lr;
    const int K4 = K >> 2, N4 = Ncol >> 2;
    const float4* A4 = (const float4*)A;
    const float4* B4 = (const float4*)B;
    float acc[4][4] = {{0.f}};
    for (int k0 = 0; k0 < K; k0 += BK) {
        float4 av = make_float4(0.f, 0.f, 0.f, 0.f);
        if (arow < M) av = A4[(long)arow * K4 + (k0 >> 2) + lc4];
        As[lc4 * 4 + 0][lr] = av.x;
        As[lc4 * 4 + 1][lr] = av.y;
        As[lc4 * 4 + 2][lr] = av.z;
        As[lc4 * 4 + 3][lr] = av.w;
        float4 bv = B4[(long)(k0 + br) * N4 + (colBase >> 2) + bc4];
        *(float4*)&Bs[br][bc4 * 4] = bv;
        __syncthreads();
#pragma unroll
        for (int k = 0; k < BK; ++k) {
            float4 a4v = *(const float4*)&As[k][ty * 4];
            float4 b4v = *(const float4*)&Bs[k][tx * 4];
            float aa[4] = {a4v.x, a4v.y, a4v.z, a4v.w};
            float bb[4] = {b4v.x, b4v.y, b4v.z, b4v.w};
#pragma unroll
            for (int i = 0; i < 4; ++i)
#pragma unroll
                for (int j = 0; j < 4; ++j)
                    acc[i][j] = fmaf(aa[i], bb[j], acc[i][j]);
        }
        __syncthreads();
    }
#pragma unroll
    for (int i = 0; i < 4; ++i) {
        int row = rowBase + ty * 4 + i;
        if (row < M) {
            ushort4 o;
            o.x = f2bf(acc[i][0]); o.y = f2bf(acc[i][1]);
            o.z = f2bf(acc[i][2]); o.w = f2bf(acc[i][3]);
            *(ushort4*)&Cb[(long)row * Ncol + colBase + tx * 4] = o;
        }
    }
}

// ====== MFMA GEMM: C = A(bf16) @ Bt(bf16), BM=128 BN=64 BK=32 ==============
template<bool RELU, bool BIAS, bool OUTBF>
__global__ __launch_bounds__(256) void k_gemm_mfma(
        const unsigned short* __restrict__ A, const unsigned short* __restrict__ Bt,
        const float* __restrict__ bias, float* __restrict__ Cf,
        unsigned short* __restrict__ Cb, int M, int K, int Ncol) {
    __shared__ unsigned short Ash[128][40];   // 80B rows: 2-way LDS (free)
    __shared__ unsigned short Bsh[64][40];
    const int tid = threadIdx.x;
    const int lane = tid & 63, w = tid >> 6;
    const int fr = lane & 15, quad = lane >> 4;
    const int wm0 = w * 32;
    const int rowBase = blockIdx.x * 128;
    const int colBase = blockIdx.y * 64;

    const int arow = tid >> 1;                 // 0..127
    const int ahalf = (tid & 1) << 4;          // 0|16 shorts
    int agrow = rowBase + arow; if (agrow >= M) agrow = M - 1;
    const long abase = (long)agrow * K + ahalf;
    const int brow = tid >> 2;                 // 0..63
    const int bseg = (tid & 3) << 3;           // 0,8,16,24
    const long bbase = (long)(colBase + brow) * K + bseg;

    f32x4 acc[2][4];
#pragma unroll
    for (int i = 0; i < 2; ++i)
#pragma unroll
        for (int j = 0; j < 4; ++j) acc[i][j] = (f32x4){0.f, 0.f, 0.f, 0.f};

    for (int k0 = 0; k0 < K; k0 += 32) {
        *(bf16x8*)&Ash[arow][ahalf]     = *(const bf16x8*)&A[abase + k0];
        *(bf16x8*)&Ash[arow][ahalf + 8] = *(const bf16x8*)&A[abase + k0 + 8];
        *(bf16x8*)&Bsh[brow][bseg]      = *(const bf16x8*)&Bt[bbase + k0];
        __syncthreads();
        bf16x8 ahf[2], bhf[4];
#pragma unroll
        for (int i = 0; i < 2; ++i)
            ahf[i] = *(const bf16x8*)&Ash[wm0 + i * 16 + fr][quad * 8];
#pragma unroll
        for (int j = 0; j < 4; ++j)
            bhf[j] = *(const bf16x8*)&Bsh[j * 16 + fr][quad * 8];
#pragma unroll
        for (int i = 0; i < 2; ++i)
#pragma unroll
            for (int j = 0; j < 4; ++j)
                acc[i][j] = __builtin_amdgcn_mfma_f32_16x16x32_bf16(
                    ahf[i], bhf[j], acc[i][j], 0, 0, 0);
        __syncthreads();
    }

    // epilogue: C layout col=lane&15, row=quad*4+reg
#pragma unroll
    for (int i = 0; i < 2; ++i) {
        const int rowb = rowBase + wm0 + i * 16 + quad * 4;
#pragma unroll
        for (int j = 0; j < 4; ++j) {
            const int col = colBase + j * 16 + fr;
            const float bv = BIAS ? bias[col] : 0.f;
#pragma unroll
            for (int r = 0; r < 4; ++r) {
                const int row = rowb + r;
                if (row < M) {
                    float v = acc[i][j][r] + bv;
                    if (RELU) v = fmaxf(v, 0.f);
                    const long o = (long)row * Ncol + col;
                    if (OUTBF) Cb[o] = f2bf(v);
                    else       Cf[o] = v;
                }
            }
        }
    }
}

// == fused heads: [mu|lv] = h2 @ Wml; z; cap — BM=64 BN=128 K=256 ===========
__global__ __launch_bounds__(256) void k_gemm_heads(
        const unsigned short* __restrict__ A, const unsigned short* __restrict__ Bt,
        const float* __restrict__ bmu, const float* __restrict__ blv,
        const float* __restrict__ eps, const float* __restrict__ Wcap,
        const float* __restrict__ bcap, float* __restrict__ mu,
        float* __restrict__ lv, unsigned short* __restrict__ Zh,
        float* __restrict__ cap, int M) {
    constexpr int K = 256;
    __shared__ unsigned short Ash[64][40];
    __shared__ unsigned short Bsh[128][40];
    const int tid = threadIdx.x;
    const int lane = tid & 63, w = tid >> 6;
    const int fr = lane & 15, quad = lane >> 4;
    const int wm0 = w * 16;
    const int rowBase = blockIdx.x * 64;

    const int arow = tid >> 2;                 // 0..63
    const int aseg = (tid & 3) << 3;
    int agrow = rowBase + arow; if (agrow >= M) agrow = M - 1;
    const long abase = (long)agrow * K + aseg;
    const int brow = tid >> 1;                 // 0..127
    const int bseg = (tid & 1) << 4;
    const long bbase = (long)brow * K + bseg;

    f32x4 acc[8];
#pragma unroll
    for (int j = 0; j < 8; ++j) acc[j] = (f32x4){0.f, 0.f, 0.f, 0.f};

    for (int k0 = 0; k0 < K; k0 += 32) {
        *(bf16x8*)&Ash[arow][aseg] = *(const bf16x8*)&A[abase + k0];
        *(bf16x8*)&Bsh[brow][bseg]     = *(const bf16x8*)&Bt[bbase + k0];
        *(bf16x8*)&Bsh[brow][bseg + 8] = *(const bf16x8*)&Bt[bbase + k0 + 8];
        __syncthreads();
        bf16x8 ahf = *(const bf16x8*)&Ash[wm0 + fr][quad * 8];
#pragma unroll
        for (int j = 0; j < 8; ++j) {
            bf16x8 bhf = *(const bf16x8*)&Bsh[j * 16 + fr][quad * 8];
            acc[j] = __builtin_amdgcn_mfma_f32_16x16x32_bf16(ahf, bhf, acc[j], 0, 0, 0);
        }
        __syncthreads();
    }

    float capacc[4] = {0.f, 0.f, 0.f, 0.f};
#pragma unroll
    for (int j = 0; j < 4; ++j) {
        const int c = j * 16 + fr;
        const float bm = bmu[c], bl = blv[c];
        const float wc = Wcap[c];
#pragma unroll
        for (int r = 0; r < 4; ++r) {
            const int row = rowBase + wm0 + quad * 4 + r;
            if (row < M) {
                const long o = (long)row * 64 + c;
                float mv = acc[j][r] + bm;
                float lvv = acc[j + 4][r] + bl;
                mu[o] = mv;
                lv[o] = lvv;
                float zz = fmaf(eps[o], expf(0.5f * lvv), mv);
                Zh[o] = f2bf(zz);
                capacc[r] = fmaf(zz, wc, capacc[r]);
            }
        }
    }
    const float b0 = bcap[0];
#pragma unroll
    for (int r = 0; r < 4; ++r) {
        float v = capacc[r];
        v += __shfl_xor(v, 1, 64);
        v += __shfl_xor(v, 2, 64);
        v += __shfl_xor(v, 4, 64);
        v += __shfl_xor(v, 8, 64);
        if (fr == 0) {
            const int row = rowBase + wm0 + quad * 4 + r;
            if (row < M) cap[row] = 1.f / (1.f + expf(-(v + b0)));
        }
    }
}

// ==== conv1 agg: h1 = relu(b1 + sum_e w_e * T[tok_e]) ======================
__global__ __launch_bounds__(256) void k_agg_tab(
        const unsigned short* __restrict__ tab, const int* __restrict__ row_ptr,
        const int2* __restrict__ packA, const float* __restrict__ bias,
        unsigned short* __restrict__ h1, int N) {
    const int wave = threadIdx.x >> 6;
    const int lane = threadIdx.x & 63;
    const int node = blockIdx.x * 4 + wave;
    if (node >= N) return;
    const ushort4* t4 = (const ushort4*)tab;
    float ax = 0.f, ay = 0.f, az = 0.f, aw = 0.f;
    const int beg = row_ptr[node], end = row_ptr[node + 1];
    int e = beg;
    for (; e + 4 <= end; e += 4) {
        int2 p0 = packA[e], p1 = packA[e + 1], p2 = packA[e + 2], p3 = packA[e + 3];
        ushort4 v0 = t4[(long)p0.y * 64 + lane];
        ushort4 v1 = t4[(long)p1.y * 64 + lane];
        ushort4 v2 = t4[(long)p2.y * 64 + lane];
        ushort4 v3 = t4[(long)p3.y * 64 + lane];
        float w0 = __int_as_float(p0.x), w1 = __int_as_float(p1.x);
        float w2 = __int_as_float(p2.x), w3 = __int_as_float(p3.x);
        ax = fmaf(bf2f(v0.x), w0, ax); ay = fmaf(bf2f(v0.y), w0, ay);
        az = fmaf(bf2f(v0.z), w0, az); aw = fmaf(bf2f(v0.w), w0, aw);
        ax = fmaf(bf2f(v1.x), w1, ax); ay = fmaf(bf2f(v1.y), w1, ay);
        az = fmaf(bf2f(v1.z), w1, az); aw = fmaf(bf2f(v1.w), w1, aw);
        ax = fmaf(bf2f(v2.x), w2, ax); ay = fmaf(bf2f(v2.y), w2, ay);
        az = fmaf(bf2f(v2.z), w2, az); aw = fmaf(bf2f(v2.w), w2, aw);
        ax = fmaf(bf2f(v3.x), w3, ax); ay = fmaf(bf2f(v3.y), w3, ay);
        az = fmaf(bf2f(v3.z), w3, az); aw = fmaf(bf2f(v3.w), w3, aw);
    }
    for (; e < end; ++e) {
        int2 p = packA[e];
        float w0 = __int_as_float(p.x);
        ushort4 v = t4[(long)p.y * 64 + lane];
        ax = fmaf(bf2f(v.x), w0, ax); ay = fmaf(bf2f(v.y), w0, ay);
        az = fmaf(bf2f(v.z), w0, az); aw = fmaf(bf2f(v.w), w0, aw);
    }
    float4 b = ((const float4*)bias)[lane];
    ax = fmaxf(ax + b.x, 0.f); ay = fmaxf(ay + b.y, 0.f);
    az = fmaxf(az + b.z, 0.f); aw = fmaxf(aw + b.w, 0.f);
    ushort4 o;
    o.x = f2bf(ax); o.y = f2bf(ay); o.z = f2bf(az); o.w = f2bf(aw);
    ((ushort4*)h1)[(long)node * 64 + lane] = o;
}

// ==== conv2 agg: a2 = sum_e w_e * h1[src_e] ================================
__global__ __launch_bounds__(256) void k_agg_nb(
        const unsigned short* __restrict__ h1, const int* __restrict__ row_ptr,
        const int2* __restrict__ packB, unsigned short* __restrict__ Ob, int N) {
    const int wave = threadIdx.x >> 6;
    const int lane = threadIdx.x & 63;
    const int node = blockIdx.x * 4 + wave;
    if (node >= N) return;
    const ushort4* h4 = (const ushort4*)h1;
    float ax = 0.f, ay = 0.f, az = 0.f, aw = 0.f;
    const int beg = row_ptr[node], end = row_ptr[node + 1];
    int e = beg;
    for (; e + 4 <= end; e += 4) {
        int2 p0 = packB[e], p1 = packB[e + 1], p2 = packB[e + 2], p3 = packB[e + 3];
        ushort4 v0 = h4[(long)p0.y * 64 + lane];
        ushort4 v1 = h4[(long)p1.y * 64 + lane];
        ushort4 v2 = h4[(long)p2.y * 64 + lane];
        ushort4 v3 = h4[(long)p3.y * 64 + lane];
        float w0 = __int_as_float(p0.x), w1 = __int_as_float(p1.x);
        float w2 = __int_as_float(p2.x), w3 = __int_as_float(p3.x);
        ax = fmaf(bf2f(v0.x), w0, ax); ay = fmaf(bf2f(v0.y), w0, ay);
        az = fmaf(bf2f(v0.z), w0, az); aw = fmaf(bf2f(v0.w), w0, aw);
        ax = fmaf(bf2f(v1.x), w1, ax); ay = fmaf(bf2f(v1.y), w1, ay);
        az = fmaf(bf2f(v1.z), w1, az); aw = fmaf(bf2f(v1.w), w1, aw);
        ax = fmaf(bf2f(v2.x), w2, ax); ay = fmaf(bf2f(v2.y), w2, ay);
        az = fmaf(bf2f(v2.z), w2, az); aw = fmaf(bf2f(v2.w), w2, aw);
        ax = fmaf(bf2f(v3.x), w3, ax); ay = fmaf(bf2f(v3.y), w3, ay);
        az = fmaf(bf2f(v3.z), w3, az); aw = fmaf(bf2f(v3.w), w3, aw);
    }
    for (; e < end; ++e) {
        int2 p = packB[e];
        float w0 = __int_as_float(p.x);
        ushort4 v = h4[(long)p.y * 64 + lane];
        ax = fmaf(bf2f(v.x), w0, ax); ay = fmaf(bf2f(v.y), w0, ay);
        az = fmaf(bf2f(v.z), w0, az); aw = fmaf(bf2f(v.w), w0, aw);
    }
    ushort4 o;
    o.x = f2bf(ax); o.y = f2bf(ay); o.z = f2bf(az); o.w = f2bf(aw);
    ((ushort4*)Ob)[(long)node * 64 + lane] = o;
}

extern "C" void kernel_launch(void* const* d_in, const int* in_sizes, int n_in,
                              void* d_out, int out_size, void* d_ws, size_t ws_size,
                              hipStream_t stream) {
    const int*   x    = (const int*)d_in[0];
    const int*   ei   = (const int*)d_in[1];
    const float* eps  = (const float*)d_in[2];
    const float* emb  = (const float*)d_in[3];
    const float* W1   = (const float*)d_in[4];
    const float* b1   = (const float*)d_in[5];
    const float* W2   = (const float*)d_in[6];
    const float* b2   = (const float*)d_in[7];
    const float* Wmu  = (const float*)d_in[8];
    const float* bmu  = (const float*)d_in[9];
    const float* Wlv  = (const float*)d_in[10];
    const float* blv  = (const float*)d_in[11];
    const float* W3   = (const float*)d_in[12];
    const float* b3   = (const float*)d_in[13];
    const float* W4   = (const float*)d_in[14];
    const float* b4   = (const float*)d_in[15];
    const float* Wcap = (const float*)d_in[16];
    const float* bcap = (const float*)d_in[17];

    const int N = in_sizes[0];
    const int E = in_sizes[1] / 2;
    const int H = in_sizes[5];            // 256
    const int L = in_sizes[9];            // 64
    const int V = in_sizes[15];           // 128
    const int F = in_sizes[4] / H;        // 128
    const int T = E + N;

    const int* src = ei;
    const int* dst = ei + E;

    // ---- workspace carve-up ----
    char* w = (char*)d_ws;
    unsigned short* h1b  = (unsigned short*)w; w += (size_t)N * H * 2;
    unsigned short* a2b  = (unsigned short*)w; w += (size_t)N * H * 2;
    unsigned short* h2b  = (unsigned short*)w; w += (size_t)N * H * 2;
    unsigned short* zh   = (unsigned short*)w; w += (size_t)N * L * 2;
    int*   degint = (int*)w;   w += (size_t)N * 4;
    int*   rowp   = (int*)w;   w += (size_t)(N + 1) * 4;
    int*   cursor = (int*)w;   w += (size_t)N * 4;
    float* dinv   = (float*)w; w += (size_t)N * 4;
    int*   bsum   = (int*)w;   w += 256 * 4;
    int2*  packA  = (int2*)w;  w += (size_t)T * 8;
    int2*  packB  = (int2*)w;  w += (size_t)T * 8;
    unsigned short* tabH = (unsigned short*)w; w += (size_t)V * H * 2;
    unsigned short* W2t  = (unsigned short*)w; w += (size_t)H * H * 2;
    unsigned short* Wml  = (unsigned short*)w; w += (size_t)H * 2 * L * 2; // [128][256]
    unsigned short* W3t  = (unsigned short*)w; w += (size_t)L * H * 2;    // [256][64]
    unsigned short* W4t  = (unsigned short*)w; w += (size_t)H * V * 2;    // [128][256]

    unsigned short* tb = a2b;   // a2 dead after GEMM2; reuse for t

    float* outp    = (float*)d_out;
    float* recon   = outp;                               // [N, V]
    float* cap     = outp + (size_t)N * V;               // [N, 1]
    float* mu      = outp + (size_t)N * V + N;           // [N, L]
    float* logvar  = mu + (size_t)N * L;                 // [N, L]

    const int nN  = (N + 255) / 256;
    const int nE  = (E + 255) / 256;
    const int nT  = (T + 255) / 256;
    const int nSc = (N + SCAN_BLOCK - 1) / SCAN_BLOCK;
    const int gM128 = (N + 127) / 128;
    const int gM64  = (N + 63) / 64;

    // ---- degree / dinv / CSR packs ----
    hipMemsetAsync(degint, 0, (size_t)N * 4, stream);
    hipMemsetAsync(cursor, 0, (size_t)N * 4, stream);
    k_deg_count<<<nE, 256, 0, stream>>>(dst, degint, E);
    k_scan_local<<<nSc, SCAN_BLOCK, 0, stream>>>(degint, rowp, bsum, dinv, N);
    k_scan_bsum<<<1, 64, 0, stream>>>(bsum, nSc);
    k_scan_add<<<nN, 256, 0, stream>>>(rowp, bsum, N, T);
    k_fill<<<nT, 256, 0, stream>>>(src, dst, x, dinv, rowp, cursor,
                                   packA, packB, E, N);

    // ---- weight conversions: one launch, 5 jobs ----
    k_cvt_all<<<dim3((H * H + 255) / 256, 5), 256, 0, stream>>>(
        W2, W2t, H, H,
        Wmu, Wml, H, L,
        Wlv, Wml + (size_t)L * H, H, L,
        W3, W3t, L, H,
        W4, W4t, H, V);

    // ---- conv1: embW1 = emb @ W1 -> bf16 table; agg -> h1 bf16 ----
    k_gemm_f32<<<dim3(V / 64, H / 64), 256, 0, stream>>>(emb, W1, tabH, V, F, H);
    k_agg_tab<<<(N + 3) / 4, 256, 0, stream>>>(tabH, rowp, packA, b1, h1b, N);

    // ---- conv2: a2 = A_hat h1; h2 = relu(a2 @ W2 + b2) -> bf16 ----
    k_agg_nb<<<(N + 3) / 4, 256, 0, stream>>>(h1b, rowp, packB, a2b, N);
    k_gemm_mfma<true, true, true><<<dim3(gM128, H / 64), 256, 0, stream>>>(
        a2b, W2t, b2, nullptr, h2b, N, H, H);

    // ---- fused heads: mu, logvar, z, cap ----
    k_gemm_heads<<<gM64, 256, 0, stream>>>(
        h2b, Wml, bmu, blv, eps, Wcap, bcap, mu, logvar, zh, cap, N);

    // ---- decode: t = relu(z@W3+b3) bf16; recon = t@W4+b4 fp32 ----
    k_gemm_mfma<true, true, true><<<dim3(gM128, H / 64), 256, 0, stream>>>(
        zh, W3t, b3, nullptr, tb, N, L, H);
    k_gemm_mfma<false, true, false><<<dim3(gM128, V / 64), 256, 0, stream>>>(
        tb, W4t, b4, recon, nullptr, N, H, V);
}